// Round 6
// baseline (4685.183 us; speedup 1.0000x reference)
//
#include <hip/hip_runtime.h>

typedef unsigned long long ull;

#define NN0 80000
#define EE0 480000
#define KK1 40000
#define KK2 20000
#define MAXAUG 4500000
#define FLATMAX 8000000
#define HASH_CAP (1u<<23)
#define HMASK (HASH_CAP-1)
#define SCH 4096
#define CDIV(a,b) (((a)+(b)-1)/(b))

// counter slots
#define C_NAUG0 0
#define C_NAUG1 1
#define C_E1 2
#define C_E2 3
#define C_T2 4
#define C_M0 5
#define C_M1 6

__device__ __forceinline__ int getE(const int* p, int s){ if(!p) return s; int e=*p; return e<s? e : s; }
__device__ __forceinline__ float leakyf(float x){ return x>0.f? x : 0.2f*x; }
__device__ __forceinline__ double leakyd(double x){ return x>0.0? x : 0.2*x; }
__device__ __forceinline__ float eluf(float x){ return x>0.f? x : (expf(x)-1.f); }

__device__ __forceinline__ ull encd(double f){ ull u=(ull)__double_as_longlong(f); return (u>>63)? ~u : (u|0x8000000000000000ULL); }

__device__ __forceinline__ unsigned hmix(ull k){
  k ^= k>>33; k *= 0xff51afd7ed558ccdULL; k ^= k>>33; k *= 0xc4ceb9fe1a85ec53ULL; k ^= k>>33;
  return (unsigned)k & HMASK;
}

// wave-aggregated counter reservation: one atomicAdd per active-branch wave
__device__ __forceinline__ int reserve_slot(int* naug){
  ull mask = __ballot(1);
  int lane = threadIdx.x & 63;
  int lead = __ffsll((long long)mask) - 1;
  int base = 0;
  if(lane==lead) base = atomicAdd(naug, (int)__popcll(mask));
  base = __shfl(base, lead, 64);
  return base + (int)__popcll(mask & ((1ULL<<lane)-1ULL));
}

// ---------------- GEMM: xl/xr projections ----------------
template<int MODE, bool DUAL>
__global__ void gemm_k(const float* __restrict__ F1, const float* __restrict__ pos,
                       const float* __restrict__ yv,
                       const float* __restrict__ W1, const float* __restrict__ W2,
                       const float* __restrict__ bias,
                       float* __restrict__ O1, float* __restrict__ O2, int N)
{
  int t = threadIdx.x;
  int row = blockIdx.x*8 + (t>>5);
  int g = (t&31)*4;
  if(row>=N) return;
  const int K = MODE==0? 11 : (MODE==1? 131 : 128);
  float a0=0,a1=0,a2=0,a3=0,b0=0,b1=0,b2=0,b3=0;
  for(int k=0;k<K;k++){
    float f;
    if(MODE==0)      f = (k<5)? F1[row*5+k] : (k<8? pos[row*3+(k-5)] : yv[0]);
    else if(MODE==1) f = (k<128)? F1[(size_t)row*128+k] : pos[row*3+(k-128)];
    else             f = F1[(size_t)row*128+k];
    float4 w = *(const float4*)(W1 + (size_t)k*128 + g);
    a0 += f*w.x; a1 += f*w.y; a2 += f*w.z; a3 += f*w.w;
    if(DUAL){
      float4 v = *(const float4*)(W2 + (size_t)k*128 + g);
      b0 += f*v.x; b1 += f*v.y; b2 += f*v.z; b3 += f*v.w;
    }
  }
  if(bias){ a0+=bias[g]; a1+=bias[g+1]; a2+=bias[g+2]; a3+=bias[g+3]; }
  float4 r; r.x=a0; r.y=a1; r.z=a2; r.w=a3;
  *(float4*)(O1+(size_t)row*128+g) = r;
  if(DUAL){ float4 r2; r2.x=b0; r2.y=b1; r2.z=b2; r2.w=b3; *(float4*)(O2+(size_t)row*128+g) = r2; }
}

// ---------------- multi-block exclusive scan (3 phases) ----------------
__global__ void scan_p1(const int* __restrict__ in, const int* pN, int Ns, int* __restrict__ bsums){
  __shared__ int red[256];
  int n = getE(pN,Ns);
  int base = blockIdx.x*SCH;
  int s=0;
  for(int i=base+threadIdx.x; i<base+SCH; i+=256) if(i<n) s+=in[i];
  red[threadIdx.x]=s; __syncthreads();
  for(int o=128;o;o>>=1){ if(threadIdx.x<(unsigned)o) red[threadIdx.x]+=red[threadIdx.x+o]; __syncthreads(); }
  if(threadIdx.x==0) bsums[blockIdx.x]=red[0];
}
__global__ void scan_p2(int* bsums, int nb){
  __shared__ int lds[256];
  int t=threadIdx.x;
  int v = (t<nb)? bsums[t] : 0;
  lds[t]=v; __syncthreads();
  for(int o=1;o<256;o<<=1){ int u=0; if(t>=o) u=lds[t-o]; __syncthreads(); lds[t]+=u; __syncthreads(); }
  if(t<nb) bsums[t]=lds[t]-v;
}
__global__ void scan_p3(const int* __restrict__ in, int* __restrict__ out, const int* pN, int Ns,
                        const int* __restrict__ bsums, int* total){
  __shared__ int tsum[256];
  int n = getE(pN,Ns);
  int base = blockIdx.x*SCH + threadIdx.x*16;
  int v[16]; int s=0;
  #pragma unroll
  for(int q=0;q<16;q++){ int i=base+q; int xv=(i<n)? in[i]:0; v[q]=s; s+=xv; }
  tsum[threadIdx.x]=s; __syncthreads();
  int mine=s;
  for(int o=1;o<256;o<<=1){ int u=0; if(threadIdx.x>=(unsigned)o) u=tsum[threadIdx.x-o]; __syncthreads(); tsum[threadIdx.x]+=u; __syncthreads(); }
  int pre = bsums[blockIdx.x] + tsum[threadIdx.x] - mine;
  #pragma unroll
  for(int q=0;q<16;q++){
    int i=base+q;
    if(i<=n){
      int val = pre+v[q];
      out[i]=val;
      if(i==n && total) *total=val;
    }
  }
}

// ---------------- CSR builders ----------------
__global__ void count_src(const int* __restrict__ es, const int* pE, int Es, int* cnts){
  int e = blockIdx.x*256+threadIdx.x; int E = getE(pE,Es); if(e>=E) return;
  atomicAdd(&cnts[es[e]], 1);
}
__global__ void fill_t2(const int* __restrict__ es, const int* __restrict__ ed, const int* pE, int Es,
                        const int* __restrict__ starts, int* cursor, int* t2){
  int e = blockIdx.x*256+threadIdx.x; int E = getE(pE,Es); if(e>=E) return;
  int s = es[e];
  int p = starts[s] + atomicAdd(&cursor[s],1);
  t2[p] = ed[e];
}
__global__ void fill_eord(const int* __restrict__ ed, const int* pE, int Es,
                          const int* __restrict__ dstarts, int* cursor, int* eord){
  int e = blockIdx.x*256+threadIdx.x; int E = getE(pE,Es); if(e>=E) return;
  int d = ed[e];
  int p = dstarts[d] + atomicAdd(&cursor[d],1);
  eord[p] = e;
}
__global__ void fill_asrcs(const int* __restrict__ augs, const int* __restrict__ augd, const int* pE, int Es,
                           const int* __restrict__ adstarts, int* cursor, int* asrcs){
  int e = blockIdx.x*256+threadIdx.x; int E = getE(pE,Es); if(e>=E) return;
  int d = augd[e];
  int p = adstarts[d] + atomicAdd(&cursor[d],1);
  asrcs[p] = augs[e];
}
// per-node mean self-loop attr via dst-CSR (no atomics)
__global__ void loop_csr_f(const int* __restrict__ es, const int* __restrict__ eord,
                           const int* __restrict__ dstarts, const float* __restrict__ pos,
                           float* __restrict__ loopat, int N)
{
  int d = blockIdx.x*256+threadIdx.x; if(d>=N) return;
  int r0=dstarts[d], r1=dstarts[d+1];
  float pd0=pos[d*3], pd1=pos[d*3+1], pd2=pos[d*3+2];
  float l0=0,l1=0,l2=0;
  for(int j=r0;j<r1;j++){
    int s = es[eord[j]];
    l0 += pd0-pos[s*3]; l1 += pd1-pos[s*3+1]; l2 += pd2-pos[s*3+2];
  }
  float inv = 1.f/fmaxf((float)(r1-r0), 1.f);
  loopat[d*3+0]=l0*inv; loopat[d*3+1]=l1*inv; loopat[d*3+2]=l2*inv;
}

// ---------------- feature GATv2 (fp32) ----------------
__global__ void feat_logits(const int* __restrict__ es, const int* __restrict__ ed, const int* pE, int Es, int N,
    const float* __restrict__ A, const float* __restrict__ B, const float* __restrict__ pos,
    const float* __restrict__ We, const float* __restrict__ att, const float* __restrict__ loopat,
    float* __restrict__ zb)
{
  int gid = blockIdx.x*blockDim.x + threadIdx.x;
  int w = gid>>6, lane = gid&63;
  int E = getE(pE,Es);
  if(w >= E+N) return;
  int s,d; float e0,e1,e2;
  if(w<E){ s=es[w]; d=ed[w]; e0=pos[d*3]-pos[s*3]; e1=pos[d*3+1]-pos[s*3+1]; e2=pos[d*3+2]-pos[s*3+2]; }
  else   { int n=w-E; s=n; d=n; e0=loopat[n*3]; e1=loopat[n*3+1]; e2=loopat[n*3+2]; }
  int c=lane, c2=lane+64;
  float m1 = A[(size_t)s*128+c ] + B[(size_t)d*128+c ] + e0*We[c ] + e1*We[128+c ] + e2*We[256+c ];
  float m2 = A[(size_t)s*128+c2] + B[(size_t)d*128+c2] + e0*We[c2] + e1*We[128+c2] + e2*We[256+c2];
  float p = leakyf(m1)*att[c] + leakyf(m2)*att[c2];
  for(int off=32; off; off>>=1) p += __shfl_down(p, off, 64);
  if(lane==0) zb[w]=p;
}

// CSR-gather softmax + aggregation + bias + elu (fused, atomic-free): one wave/node, 2 ch/lane
__global__ void feat_acc_csr(const int* __restrict__ es, const int* __restrict__ eord,
                             const int* __restrict__ dstarts, const int* pE, int Es,
                             const float* __restrict__ A, const float* __restrict__ zb,
                             const float* __restrict__ bias, float* __restrict__ h, int N)
{
  int w = (blockIdx.x*256+threadIdx.x)>>6;
  int lane = threadIdx.x&63;
  if(w>=N) return;
  int E = getE(pE,Es);
  int r0=dstarts[w], r1=dstarts[w+1];
  // max logit (lane-parallel over edges)
  float mx = zb[E+w];
  for(int j=r0+lane; j<r1; j+=64) mx = fmaxf(mx, zb[eord[j]]);
  for(int o=32;o;o>>=1) mx = fmaxf(mx, __shfl_down(mx,o,64));
  mx = __shfl(mx, 0, 64);
  // accumulate (serial edges, channel-parallel lanes)
  float denom = 0.f;
  float2 acc; acc.x=0.f; acc.y=0.f;
  for(int j=r0;j<r1;j++){
    int e = eord[j]; int s = es[e];
    float z = expf(zb[e]-mx);
    denom += z;
    float2 v = *(const float2*)(A + (size_t)s*128 + lane*2);
    acc.x += z*v.x; acc.y += z*v.y;
  }
  { // self loop
    float z = expf(zb[E+w]-mx);
    denom += z;
    float2 v = *(const float2*)(A + (size_t)w*128 + lane*2);
    acc.x += z*v.x; acc.y += z*v.y;
  }
  float inv = 1.f/denom;
  float2 bb = *(const float2*)(bias + lane*2);
  acc.x = eluf(acc.x*inv + bb.x); acc.y = eluf(acc.y*inv + bb.y);
  *(float2*)(h + (size_t)w*128 + lane*2) = acc;
}

// ---------------- score GATv2 (fp64, C_out=1) ----------------
__global__ void gemm_score(const float* __restrict__ h, const float* __restrict__ pos,
                           const float* __restrict__ pWl, const float* __restrict__ pWr,
                           double* __restrict__ xls, double* __restrict__ xrs, int N)
{
  int n = blockIdx.x*256+threadIdx.x; if(n>=N) return;
  double sl=0, sr=0;
  for(int k=0;k<128;k++){ double f=h[(size_t)n*128+k]; sl+=f*(double)pWl[k]; sr+=f*(double)pWr[k]; }
  for(int d=0;d<3;d++){ double f=pos[n*3+d]; sl+=f*(double)pWl[128+d]; sr+=f*(double)pWr[128+d]; }
  xls[n]=sl; xrs[n]=sr;
}

// fused score GATv2 over aug dst-CSR: one wave per node, two lane-parallel passes
__global__ void score_fused(const int* __restrict__ asrcs, const int* __restrict__ adstarts,
                            const float* __restrict__ pos,
                            const double* __restrict__ xls, const double* __restrict__ xrs,
                            const float* __restrict__ pWe, const float* __restrict__ paP,
                            const float* __restrict__ pbP,
                            double* __restrict__ score, int N)
{
  int w = (blockIdx.x*256+threadIdx.x)>>6;
  int lane = threadIdx.x&63;
  if(w>=N) return;
  int r0=adstarts[w], r1=adstarts[w+1];
  float pd0=pos[w*3], pd1=pos[w*3+1], pd2=pos[w*3+2];
  double w0=(double)pWe[0], w1=(double)pWe[1], w2=(double)pWe[2], pa=(double)paP[0];
  double xrd=xrs[w];
  // pass 0: loop-attr sums + max logit
  double mx=-1e300, s0=0, s1=0, s2=0;
  for(int j=r0+lane; j<r1; j+=64){
    int s = asrcs[j];
    double e0=(double)(pd0-pos[s*3]), e1=(double)(pd1-pos[s*3+1]), e2=(double)(pd2-pos[s*3+2]);
    s0+=e0; s1+=e1; s2+=e2;
    double lg = leakyd(xls[s]+xrd + e0*w0+e1*w1+e2*w2) * pa;
    mx = fmax(mx, lg);
  }
  for(int o=32;o;o>>=1){
    mx = fmax(mx, __shfl_down(mx,o,64));
    s0 += __shfl_down(s0,o,64);
    s1 += __shfl_down(s1,o,64);
    s2 += __shfl_down(s2,o,64);
  }
  mx = __shfl(mx,0,64); s0=__shfl(s0,0,64); s1=__shfl(s1,0,64); s2=__shfl(s2,0,64);
  int deg = r1-r0;
  double invd = 1.0/(double)(deg>0? deg : 1);
  double l0=s0*invd, l1=s1*invd, l2=s2*invd;
  double lg_self = leakyd(xls[w]+xrd + l0*w0+l1*w1+l2*w2) * pa;
  mx = fmax(mx, lg_self);
  // pass 1: denom + weighted sum
  double den=0, acc=0;
  for(int j=r0+lane; j<r1; j+=64){
    int s = asrcs[j];
    double e0=(double)(pd0-pos[s*3]), e1=(double)(pd1-pos[s*3+1]), e2=(double)(pd2-pos[s*3+2]);
    double lg = leakyd(xls[s]+xrd + e0*w0+e1*w1+e2*w2) * pa;
    double z = exp(lg-mx);
    den += z; acc += z*xls[s];
  }
  for(int o=32;o;o>>=1){
    den += __shfl_down(den,o,64);
    acc += __shfl_down(acc,o,64);
  }
  if(lane==0){
    double z = exp(lg_self-mx);
    den += z; acc += z*xls[w];
    score[w] = tanh(acc/den + (double)pbP[0]);
  }
}

// ---------------- augment: hash insert ----------------
__device__ __forceinline__ void hinsert(ull* tab, ull key, int s, int b, int* augs, int* augd, int* naug){
  unsigned h = hmix(key);
  for(;;){
    ull old = atomicCAS(&tab[h], 0xFFFFFFFFFFFFFFFFULL, key);
    if(old==0xFFFFFFFFFFFFFFFFULL){
      int i = reserve_slot(naug);
      if(i<MAXAUG){ augs[i]=s; augd[i]=b; }
      return;
    }
    if(old==key) return;
    h = (h+1)&HMASK;
  }
}

__global__ void insert1(const int* __restrict__ es, const int* __restrict__ ed, const int* pE, int Es, int N,
                        ull* tab, int* augs, int* augd, int* naug){
  int e = blockIdx.x*256+threadIdx.x; int E = getE(pE,Es); if(e>=E) return;
  int s=es[e], t=ed[e];
  hinsert(tab, (ull)((long long)s*N+t), s, t, augs, augd, naug);
}

__global__ void edge_lens(const int* __restrict__ ed, const int* pE, int Es,
                          const int* __restrict__ cnts, int* __restrict__ lens){
  int e = blockIdx.x*256+threadIdx.x; int E = getE(pE,Es); if(e>=E) return;
  lens[e] = cnts[ed[e]];
}

// one thread per 2-hop candidate; edge located by binary search in scanned lens
__global__ void insert2_flat(const int* __restrict__ es, const int* __restrict__ ed, const int* pE, int Es,
                             const int* __restrict__ l2scan, const int* __restrict__ pT,
                             const int* __restrict__ starts, const int* __restrict__ t2, int N,
                             ull* tab, int* augs, int* augd, int* naug)
{
  int tid = blockIdx.x*256+threadIdx.x;
  if(tid >= *pT) return;
  int E = getE(pE,Es);
  int lo=0, hi=E;
  while(hi-lo>1){ int mid=(lo+hi)>>1; if(l2scan[mid]<=tid) lo=mid; else hi=mid; }
  int e = lo;
  int j = tid - l2scan[e];
  int s = es[e], t = ed[e];
  int b = t2[starts[t]+j];
  hinsert(tab, (ull)((long long)s*N+b), s, b, augs, augd, naug);
}

// ---------------- top-k: exact radix select + candidate ranking ----------------
__global__ void enc_scores(const double* __restrict__ score, int N, ull* __restrict__ ek){
  int i = blockIdx.x*256+threadIdx.x; if(i>=N) return;
  ek[i] = encd(score[i]);
}
// histogram of 16-bit digit at `shift` over keys matching the selected prefix
__global__ void hist_k(const ull* __restrict__ ek, int N, int shift, const ull* __restrict__ selT,
                       int* __restrict__ hist){
  int i = blockIdx.x*256+threadIdx.x; if(i>=N) return;
  ull key = ek[i];
  if(shift<48){
    ull pref = *selT;
    if((key >> (shift+16)) != (pref >> (shift+16))) return;
  }
  atomicAdd(&hist[(int)((key>>shift)&0xFFFF)], 1);
}
__global__ void part_k(const int* __restrict__ hist, int* __restrict__ partial){
  __shared__ int red[256];
  int v = hist[blockIdx.x*256+threadIdx.x];
  red[threadIdx.x]=v; __syncthreads();
  for(int o=128;o;o>>=1){ if(threadIdx.x<(unsigned)o) red[threadIdx.x]+=red[threadIdx.x+o]; __syncthreads(); }
  if(threadIdx.x==0) partial[blockIdx.x]=red[0];
}
__global__ void findbin_k(const int* __restrict__ hist, const int* __restrict__ partial,
                          ull* selT, int* selRB, int k, int shift){
  __shared__ int sfx[256];
  __shared__ int hh[256];
  __shared__ int sfh[256];
  __shared__ int c_star, rb2s;
  int t=threadIdx.x;
  // suffix (inclusive) sums of chunk partials
  sfx[t]=partial[t]; __syncthreads();
  for(int o=1;o<256;o<<=1){
    int u = (t+o<256)? sfx[t+o] : 0;
    __syncthreads(); sfx[t]+=u; __syncthreads();
  }
  int rb = *selRB;
  if( rb+sfx[t] >= k && (t==255 || rb+sfx[t+1] < k) ) c_star = t;
  __syncthreads();
  int cs = c_star;
  // suffix sums within the crossing chunk
  hh[t] = hist[cs*256+t]; sfh[t]=hh[t]; __syncthreads();
  for(int o=1;o<256;o<<=1){
    int u = (t+o<256)? sfh[t+o] : 0;
    __syncthreads(); sfh[t]+=u; __syncthreads();
  }
  if(t==0) rb2s = rb + (cs<255? sfx[cs+1] : 0);
  __syncthreads();
  int rb2 = rb2s;
  if( rb2+sfh[t] >= k && (t==255 || rb2+sfh[t+1] < k) ){
    *selT |= ((ull)(cs*256+t)) << shift;
    *selRB = rb2 + (t<255? sfh[t+1] : 0);
  }
}
__global__ void compact_k(const ull* __restrict__ ek, int N, const ull* __restrict__ selT,
                          ull* __restrict__ ckey, int* __restrict__ cidx, int* pM){
  int i = blockIdx.x*256+threadIdx.x; if(i>=N) return;
  ull key = ek[i];
  if(key >= *selT){
    int p = reserve_slot(pM);
    ckey[p]=key; cidx[p]=i;
  }
}
__global__ void zerocand_k(const int* __restrict__ cidx, const int* pM, int* __restrict__ rank){
  int i = blockIdx.x*256+threadIdx.x; if(i>=*pM) return;
  rank[cidx[i]] = 0;
}
// pairwise rank among candidates only (M ~= k)
__global__ void rank_cand(const ull* __restrict__ ckey, const int* __restrict__ cidx, const int* pM,
                          int jlen, int* __restrict__ rank){
  __shared__ ull tk[1024];
  __shared__ int ti[1024];
  int M = *pM;
  if(blockIdx.x*256 >= M) return;            // block-uniform early out
  int i = blockIdx.x*256+threadIdx.x;
  ull ki = 0; int ii = 0x7FFFFFFF;
  if(i<M){ ki=ckey[i]; ii=cidx[i]; }
  int jbeg = blockIdx.y*jlen;
  int jend = jbeg+jlen; if(jend>M) jend=M;
  int c0=0,c1=0,c2=0,c3=0;
  for(int bb=jbeg; bb<jend; bb+=1024){
    for(int j=threadIdx.x; j<1024; j+=256){
      int idx=bb+j;
      tk[j] = (idx<jend)? ckey[idx] : 0ULL;
      ti[j] = (idx<jend)? cidx[idx] : 0x7FFFFFFF;
    }
    __syncthreads();
    #pragma unroll 4
    for(int j=0;j<1024;j+=4){
      ull s0=tk[j],s1=tk[j+1],s2=tk[j+2],s3=tk[j+3];
      int a0=ti[j],a1=ti[j+1],a2=ti[j+2],a3=ti[j+3];
      c0 += (s0>ki)||(s0==ki && a0<ii);
      c1 += (s1>ki)||(s1==ki && a1<ii);
      c2 += (s2>ki)||(s2==ki && a2<ii);
      c3 += (s3>ki)||(s3==ki && a3<ii);
    }
    __syncthreads();
  }
  if(i<M){ int c=(c0+c1)+(c2+c3); if(c) atomicAdd(&rank[ii], c); }
}
__global__ void scatter_perm(const int* __restrict__ rank, int N, int k, int* __restrict__ perm){
  int i = blockIdx.x*256+threadIdx.x; if(i>=N) return;
  int r = rank[i]; if(r<k) perm[r]=i;
}
__global__ void pool_gather(const float* __restrict__ h, const double* __restrict__ score,
                            const int* __restrict__ perm, int k, float* __restrict__ outA){
  int idx = blockIdx.x*256+threadIdx.x; if(idx>=k*32) return;
  int r = idx>>5, g = (idx&31)*4;
  int p = perm[r]; float sc = (float)score[p];
  const float4 x = *(const float4*)(h + (size_t)p*128 + g);
  float4 o; o.x=x.x*sc; o.y=x.y*sc; o.z=x.z*sc; o.w=x.w*sc;
  *(float4*)(outA + (size_t)r*128 + g) = o;
}
__global__ void pos_gather(const float* __restrict__ posc, const int* __restrict__ perm, int k, float* __restrict__ posn){
  int idx = blockIdx.x*256+threadIdx.x; if(idx>=k*3) return;
  int r = idx/3, j = idx-r*3;
  posn[idx] = posc[perm[r]*3+j];
}

// ---------------- filter_adj ----------------
__global__ void filter_flags(const int* __restrict__ es, const int* __restrict__ ed, const int* pE, int Es,
                             const int* __restrict__ rank, int k, int* __restrict__ flags){
  int e = blockIdx.x*256+threadIdx.x; int E = getE(pE,Es); if(e>=E) return;
  flags[e] = (rank[es[e]]<k && rank[ed[e]]<k) ? 1 : 0;
}
__global__ void filter_write(const int* __restrict__ es, const int* __restrict__ ed, const int* pE, int Es,
                             const int* __restrict__ rank, int k, const int* __restrict__ scanout,
                             int* __restrict__ ns, int* __restrict__ nd){
  int e = blockIdx.x*256+threadIdx.x; int E = getE(pE,Es); if(e>=E) return;
  int rs = rank[es[e]], rd = rank[ed[e]];
  if(rs<k && rd<k){ int p = scanout[e]; ns[p]=rs; nd[p]=rd; }
}

// ---------------- output emit ----------------
__global__ void calc_offsets(const int* __restrict__ cnt, long long* __restrict__ offs){
  if(blockIdx.x==0 && threadIdx.x==0){
    long long E1 = cnt[C_E1], E2 = cnt[C_E2];
    long long o = (long long)KK2*128;
    offs[0]=0;
    offs[1]=o; o += 2*E2;
    offs[2]=o; o += 2*E1;
    offs[3]=o; o += 2*(long long)EE0;
    offs[4]=o; o += (long long)KK2*3;
    offs[5]=o; o += (long long)KK1*3;
    offs[6]=o; o += (long long)NN0*3;
    offs[7]=o; o += 3*E2;
    offs[8]=o; o += 3*E1;
    offs[9]=o;
  }
}
__global__ void emit_pe(const int* __restrict__ s, const int* __restrict__ d, const int* pE, int Es,
                        const long long* __restrict__ offs, int oi, float* __restrict__ out){
  int e = blockIdx.x*256+threadIdx.x; int E = getE(pE,Es); if(e>=E) return;
  long long o = offs[oi];
  out[o+e]   = (float)s[e];
  out[o+E+e] = (float)d[e];
}
__global__ void emit_pp(const float* __restrict__ p, int n, const long long* __restrict__ offs, int oi, float* __restrict__ out){
  int i = blockIdx.x*256+threadIdx.x; if(i>=n) return;
  out[offs[oi]+i] = p[i];
}
__global__ void emit_eas(const int* __restrict__ s, const int* __restrict__ d, const int* pE, int Es,
                         const float* __restrict__ pos, const long long* __restrict__ offs, int oi, float* __restrict__ out){
  int e = blockIdx.x*256+threadIdx.x; int E = getE(pE,Es); if(e>=E) return;
  long long o = offs[oi];
  int ss=s[e], dd=d[e];
  out[o+3*e+0] = pos[dd*3+0]-pos[ss*3+0];
  out[o+3*e+1] = pos[dd*3+1]-pos[ss*3+1];
  out[o+3*e+2] = pos[dd*3+2]-pos[ss*3+2];
}

// =======================================================================
extern "C" void kernel_launch(void* const* d_in, const int* in_sizes, int n_in,
                              void* d_out, int out_size, void* d_ws, size_t ws_size,
                              hipStream_t stream)
{
  const float* x    = (const float*)d_in[0];
  const float* yv   = (const float*)d_in[1];
  const float* pos0 = (const float*)d_in[2];
  const int*   ei   = (const int*)d_in[3];
  const float* Wl0  = (const float*)d_in[4];
  const float* Wr0  = (const float*)d_in[5];
  const float* We0  = (const float*)d_in[6];
  const float* a0   = (const float*)d_in[7];
  const float* b0   = (const float*)d_in[8];
  const float* Wls  = (const float*)d_in[9];
  const float* Wrs  = (const float*)d_in[10];
  const float* Wes  = (const float*)d_in[11];
  const float* atts = (const float*)d_in[12];
  const float* bs   = (const float*)d_in[13];
  const float* pWl  = (const float*)d_in[14];
  const float* pWr  = (const float*)d_in[15];
  const float* pWe  = (const float*)d_in[16];
  const float* pa   = (const float*)d_in[17];
  const float* pb   = (const float*)d_in[18];
  const float* linW = (const float*)d_in[19];
  const float* linb = (const float*)d_in[20];
  float* out = (float*)d_out;

  const int* eisrc = ei;
  const int* eidst = ei + EE0;

  // ---- workspace layout ----
  char* base = (char*)d_ws; size_t off = 0;
  auto alloc = [&](size_t b)->void*{
    off = (off + 255) & ~(size_t)255;
    void* p = base + off; off += b; return p;
  };
  int*       cnt     = (int*)alloc(64*4);
  long long* offs    = (long long*)alloc(16*8);
  int*       bsums   = (int*)alloc(256*4);
  ull*       sel     = (ull*)alloc(2*8);       // sel[0]=threshold prefix, sel[1] low half used as rank_base
  int*       hist    = (int*)alloc(65536*4);
  int*       partial = (int*)alloc(256*4);
  double*    xls     = (double*)alloc((size_t)NN0*8);
  double*    xrs     = (double*)alloc((size_t)NN0*8);
  double*    score   = (double*)alloc((size_t)NN0*8);
  ull*       ek      = (ull*)alloc((size_t)NN0*8);
  ull*       ckey    = (ull*)alloc((size_t)NN0*8);
  int*       cidx    = (int*)alloc((size_t)NN0*4);
  float*     loopatF = (float*)alloc((size_t)NN0*12);
  int*       rank    = (int*)alloc((size_t)NN0*4);
  int*       perm    = (int*)alloc((size_t)NN0*4);
  int*       cntsrc  = (int*)alloc((size_t)NN0*4);
  int*       starts  = (int*)alloc((size_t)(NN0+1)*4);
  int*       cursor  = (int*)alloc((size_t)NN0*4);
  int*       cntdst  = (int*)alloc((size_t)NN0*4);
  int*       dstarts = (int*)alloc((size_t)(NN0+1)*4);
  int*       adstarts= (int*)alloc((size_t)(NN0+1)*4);
  int*       eord    = (int*)alloc((size_t)EE0*4);
  int*       lens    = (int*)alloc((size_t)EE0*4);
  int*       l2scan  = (int*)alloc((size_t)(EE0+1)*4);
  int*       t2      = (int*)alloc((size_t)EE0*4);
  int*       flags   = (int*)alloc((size_t)EE0*4);
  int*       scanout = (int*)alloc((size_t)(EE0+1)*4);
  int*       eb0s    = (int*)alloc((size_t)EE0*4);
  int*       eb0d    = (int*)alloc((size_t)EE0*4);
  int*       eb1s    = (int*)alloc((size_t)EE0*4);
  int*       eb1d    = (int*)alloc((size_t)EE0*4);
  float*     pos1    = (float*)alloc((size_t)KK1*12);
  float*     pos2    = (float*)alloc((size_t)KK2*12);
  float*     A       = (float*)alloc((size_t)NN0*128*4);
  float*     B       = (float*)alloc((size_t)NN0*128*4);
  float*     h       = (float*)alloc((size_t)NN0*128*4);
  int*       augs    = (int*)alloc((size_t)MAXAUG*4);
  int*       augd    = (int*)alloc((size_t)MAXAUG*4);
  size_t uni_bytes = (size_t)HASH_CAP*8;
  void*      uni     = alloc(uni_bytes);   // union: hash table / zbF
  if(off > ws_size) return;  // workspace insufficient — fail visibly

  // asrcs (aug dst-CSR sources, 18MB) aliases B (40.96MB): B is dead during
  // the pool stage, and score_fused finishes with asrcs before the next
  // feat_conv touches B.
  int*    asrcs = (int*)B;
  float*  zbF = (float*)uni;
  ull*    tab = (ull*)uni;
  ull*    selT  = sel;
  int*    selRB = (int*)(sel+1);

  hipMemsetAsync(cnt, 0, 64*4, stream);

  // ---- multi-block exclusive scan ----
  auto scan = [&](const int* in, int* sout, const int* pN, int Ns, int* total){
    int nb = CDIV(Ns+1, SCH);
    scan_p1<<<nb,256,0,stream>>>(in,pN,Ns,bsums);
    scan_p2<<<1,256,0,stream>>>(bsums,nb);
    scan_p3<<<nb,256,0,stream>>>(in,sout,pN,Ns,bsums,total);
  };

  // ---- dst-CSR + self-loop attrs for a graph (built once, reused by its convs) ----
  auto build_csr_dst = [&](const int* es, const int* ed, const int* pE, int Emax, int N, const float* pcur){
    hipMemsetAsync(cntdst,0,(size_t)N*4,stream);
    count_src<<<CDIV(Emax,256),256,0,stream>>>(ed,pE,Emax,cntdst);   // count by dst
    scan(cntdst,dstarts,nullptr,N,nullptr);
    hipMemsetAsync(cursor,0,(size_t)N*4,stream);
    fill_eord<<<CDIV(Emax,256),256,0,stream>>>(ed,pE,Emax,dstarts,cursor,eord);
    loop_csr_f<<<CDIV(N,256),256,0,stream>>>(es,eord,dstarts,pcur,loopatF,N);
  };

  // ---- feature GATv2 conv (fp32, CSR-gather aggregation, fused softmax) ----
  auto feat_conv = [&](const float* Wl, const float* Wr, const float* We, const float* att, const float* bias,
                       const int* es, const int* ed, const int* pE, int Emax, int N, const float* pcur,
                       bool conv0mode){
    if(conv0mode)
      gemm_k<0,true><<<CDIV(N,8),256,0,stream>>>(x,pcur,yv,Wl,Wr,nullptr,A,B,N);
    else
      gemm_k<1,true><<<CDIV(N,8),256,0,stream>>>(h,pcur,nullptr,Wl,Wr,nullptr,A,B,N);
    long long wt = (long long)(Emax+N)*64;
    feat_logits<<<(int)CDIV(wt,256),256,0,stream>>>(es,ed,pE,Emax,N,A,B,pcur,We,att,loopatF,zbF);
    feat_acc_csr<<<CDIV(N*64,256),256,0,stream>>>(es,eord,dstarts,pE,Emax,A,zbF,bias,h,N);
  };

  // ---- SAGPool stage ----
  auto pool = [&](int l, int N, int k, const int* es, const int* ed, const int* pE, int Emax,
                  const float* pcur, float* pnext, int* ns, int* nd, int naugslot, int eslot, int cmslot){
    // augment: A + A@A via src-CSR + hash dedupe
    hipMemsetAsync(uni, 0xFF, (size_t)HASH_CAP*8, stream);
    hipMemsetAsync(cntsrc, 0, (size_t)N*4, stream);
    count_src<<<CDIV(Emax,256),256,0,stream>>>(es,pE,Emax,cntsrc);
    scan(cntsrc,starts,nullptr,N,nullptr);
    hipMemsetAsync(cursor, 0, (size_t)N*4, stream);
    fill_t2<<<CDIV(Emax,256),256,0,stream>>>(es,ed,pE,Emax,starts,cursor,t2);
    edge_lens<<<CDIV(Emax,256),256,0,stream>>>(ed,pE,Emax,cntsrc,lens);
    scan(lens,l2scan,pE,Emax,cnt+C_T2);
    insert1<<<CDIV(Emax,256),256,0,stream>>>(es,ed,pE,Emax,N,tab,augs,augd,cnt+naugslot);
    insert2_flat<<<CDIV(FLATMAX,256),256,0,stream>>>(es,ed,pE,Emax,l2scan,cnt+C_T2,starts,t2,N,tab,augs,augd,cnt+naugslot);
    // aug dst-CSR
    hipMemsetAsync(cntdst,0,(size_t)N*4,stream);
    count_src<<<CDIV(MAXAUG,256),256,0,stream>>>(augd,cnt+naugslot,MAXAUG,cntdst);
    scan(cntdst,adstarts,nullptr,N,nullptr);
    hipMemsetAsync(cursor,0,(size_t)N*4,stream);
    fill_asrcs<<<CDIV(MAXAUG,256),256,0,stream>>>(augs,augd,cnt+naugslot,MAXAUG,adstarts,cursor,asrcs);
    // fused score GATv2 (fp64)
    gemm_score<<<CDIV(N,256),256,0,stream>>>(h,pcur,pWl+l*131,pWr+l*131,xls,xrs,N);
    score_fused<<<CDIV(N*64,256),256,0,stream>>>(asrcs,adstarts,pcur,xls,xrs,pWe+l*3,pa+l,pb+l,score,N);
    // top-k: exact 4-round radix select, then rank among candidates only
    enc_scores<<<CDIV(N,256),256,0,stream>>>(score,N,ek);
    hipMemsetAsync(sel,0,16,stream);
    for(int r=0;r<4;r++){
      int sh = 48-16*r;
      hipMemsetAsync(hist,0,65536*4,stream);
      hist_k<<<CDIV(N,256),256,0,stream>>>(ek,N,sh,selT,hist);
      part_k<<<256,256,0,stream>>>(hist,partial);
      findbin_k<<<1,256,0,stream>>>(hist,partial,selT,selRB,k,sh);
    }
    compact_k<<<CDIV(N,256),256,0,stream>>>(ek,N,selT,ckey,cidx,cnt+cmslot);
    hipMemsetAsync(rank,0x3f,(size_t)N*4,stream);
    zerocand_k<<<CDIV(N,256),256,0,stream>>>(cidx,cnt+cmslot,rank);
    {
      int jch = 8, jlen = CDIV(N,jch);
      dim3 g(CDIV(N,256), jch);
      rank_cand<<<g,256,0,stream>>>(ckey,cidx,cnt+cmslot,jlen,rank);
    }
    scatter_perm<<<CDIV(N,256),256,0,stream>>>(rank,N,k,perm);
    pool_gather<<<CDIV(k*32,256),256,0,stream>>>(h,score,perm,k,A);
    hipMemcpyAsync(h,A,(size_t)k*128*4,hipMemcpyDeviceToDevice,stream);
    pos_gather<<<CDIV(k*3,256),256,0,stream>>>(pcur,perm,k,pnext);
    // filter_adj (stable)
    filter_flags<<<CDIV(Emax,256),256,0,stream>>>(es,ed,pE,Emax,rank,k,flags);
    scan(flags,scanout,pE,Emax,cnt+eslot);
    filter_write<<<CDIV(Emax,256),256,0,stream>>>(es,ed,pE,Emax,rank,k,scanout,ns,nd);
  };

  // ================= pipeline =================
  build_csr_dst(eisrc,eidst,nullptr,EE0, NN0, pos0);
  feat_conv(Wl0,Wr0,We0,a0,b0, eisrc,eidst,nullptr,EE0, NN0, pos0, true);
  feat_conv(Wls+0*16768,Wrs+0*16768,Wes+0*384,atts+0*128,bs+0*128, eisrc,eidst,nullptr,EE0, NN0, pos0, false);
  pool(0, NN0, KK1, eisrc,eidst,nullptr,EE0, pos0,pos1, eb0s,eb0d, C_NAUG0, C_E1, C_M0);
  build_csr_dst(eb0s,eb0d,cnt+C_E1,EE0, KK1, pos1);
  feat_conv(Wls+1*16768,Wrs+1*16768,Wes+1*384,atts+1*128,bs+1*128, eb0s,eb0d,cnt+C_E1,EE0, KK1, pos1, false);
  pool(1, KK1, KK2, eb0s,eb0d,cnt+C_E1,EE0, pos1,pos2, eb1s,eb1d, C_NAUG1, C_E2, C_M1);
  build_csr_dst(eb1s,eb1d,cnt+C_E2,EE0, KK2, pos2);
  feat_conv(Wls+2*16768,Wrs+2*16768,Wes+2*384,atts+2*128,bs+2*128, eb1s,eb1d,cnt+C_E2,EE0, KK2, pos2, false);
  feat_conv(Wls+3*16768,Wrs+3*16768,Wes+3*384,atts+3*128,bs+3*128, eb1s,eb1d,cnt+C_E2,EE0, KK2, pos2, false);
  gemm_k<2,false><<<CDIV(KK2,8),256,0,stream>>>(h,nullptr,nullptr,linW,nullptr,linb,out,nullptr,KK2);

  // ---- emit remaining outputs ----
  calc_offsets<<<1,32,0,stream>>>(cnt,offs);
  emit_pe <<<CDIV(EE0,256),256,0,stream>>>(eb1s,eb1d,cnt+C_E2,EE0,offs,1,out);
  emit_pe <<<CDIV(EE0,256),256,0,stream>>>(eb0s,eb0d,cnt+C_E1,EE0,offs,2,out);
  emit_pe <<<CDIV(EE0,256),256,0,stream>>>(eisrc,eidst,nullptr,EE0,offs,3,out);
  emit_pp <<<CDIV(KK2*3,256),256,0,stream>>>(pos2,KK2*3,offs,4,out);
  emit_pp <<<CDIV(KK1*3,256),256,0,stream>>>(pos1,KK1*3,offs,5,out);
  emit_pp <<<CDIV(NN0*3,256),256,0,stream>>>(pos0,NN0*3,offs,6,out);
  emit_eas<<<CDIV(EE0,256),256,0,stream>>>(eb1s,eb1d,cnt+C_E2,EE0,pos2,offs,7,out);
  emit_eas<<<CDIV(EE0,256),256,0,stream>>>(eb0s,eb0d,cnt+C_E1,EE0,pos1,offs,8,out);
  emit_eas<<<CDIV(EE0,256),256,0,stream>>>(eisrc,eidst,nullptr,EE0,pos0,offs,9,out);
}

// Round 7
// 3436.090 us; speedup vs baseline: 1.3635x; 1.3635x over previous
//
#include <hip/hip_runtime.h>

typedef unsigned long long ull;

#define NN0 80000
#define EE0 480000
#define KK1 40000
#define KK2 20000
#define FLATMAX 8000000
#define SCH 4096
#define CDIV(a,b) (((a)+(b)-1)/(b))
#define HBINS (1<<21)

// counter slots
#define C_E1 2
#define C_E2 3
#define C_T2 4
#define C_M0 5
#define C_M1 6

__device__ __forceinline__ int getE(const int* p, int s){ if(!p) return s; int e=*p; return e<s? e : s; }
__device__ __forceinline__ float leakyf(float x){ return x>0.f? x : 0.2f*x; }
__device__ __forceinline__ double leakyd(double x){ return x>0.0? x : 0.2*x; }
__device__ __forceinline__ float eluf(float x){ return x>0.f? x : (expf(x)-1.f); }

__device__ __forceinline__ ull encd(double f){ ull u=(ull)__double_as_longlong(f); return (u>>63)? ~u : (u|0x8000000000000000ULL); }

__device__ __forceinline__ int reserve_slot(int* ctr){
  ull mask = __ballot(1);
  int lane = threadIdx.x & 63;
  int lead = __ffsll((long long)mask) - 1;
  int base = 0;
  if(lane==lead) base = atomicAdd(ctr, (int)__popcll(mask));
  base = __shfl(base, lead, 64);
  return base + (int)__popcll(mask & ((1ULL<<lane)-1ULL));
}

// ---------------- GEMM: xl/xr projections ----------------
template<int MODE, bool DUAL>
__global__ void gemm_k(const float* __restrict__ F1, const float* __restrict__ pos,
                       const float* __restrict__ yv,
                       const float* __restrict__ W1, const float* __restrict__ W2,
                       const float* __restrict__ bias,
                       float* __restrict__ O1, float* __restrict__ O2, int N)
{
  int t = threadIdx.x;
  int row = blockIdx.x*8 + (t>>5);
  int g = (t&31)*4;
  if(row>=N) return;
  const int K = MODE==0? 11 : (MODE==1? 131 : 128);
  float a0=0,a1=0,a2=0,a3=0,b0=0,b1=0,b2=0,b3=0;
  for(int k=0;k<K;k++){
    float f;
    if(MODE==0)      f = (k<5)? F1[row*5+k] : (k<8? pos[row*3+(k-5)] : yv[0]);
    else if(MODE==1) f = (k<128)? F1[(size_t)row*128+k] : pos[row*3+(k-128)];
    else             f = F1[(size_t)row*128+k];
    float4 w = *(const float4*)(W1 + (size_t)k*128 + g);
    a0 += f*w.x; a1 += f*w.y; a2 += f*w.z; a3 += f*w.w;
    if(DUAL){
      float4 v = *(const float4*)(W2 + (size_t)k*128 + g);
      b0 += f*v.x; b1 += f*v.y; b2 += f*v.z; b3 += f*v.w;
    }
  }
  if(bias){ a0+=bias[g]; a1+=bias[g+1]; a2+=bias[g+2]; a3+=bias[g+3]; }
  float4 r; r.x=a0; r.y=a1; r.z=a2; r.w=a3;
  *(float4*)(O1+(size_t)row*128+g) = r;
  if(DUAL){ float4 r2; r2.x=b0; r2.y=b1; r2.z=b2; r2.w=b3; *(float4*)(O2+(size_t)row*128+g) = r2; }
}

// ---------------- multi-block exclusive scan ----------------
__global__ void scan_p1(const int* __restrict__ in, const int* pN, int Ns, int* __restrict__ bsums){
  __shared__ int red[256];
  int n = getE(pN,Ns);
  int base = blockIdx.x*SCH;
  int s=0;
  for(int i=base+threadIdx.x; i<base+SCH; i+=256) if(i<n) s+=in[i];
  red[threadIdx.x]=s; __syncthreads();
  for(int o=128;o;o>>=1){ if(threadIdx.x<(unsigned)o) red[threadIdx.x]+=red[threadIdx.x+o]; __syncthreads(); }
  if(threadIdx.x==0) bsums[blockIdx.x]=red[0];
}
__global__ void scan_p2(int* bsums, int nb){
  __shared__ int lds[256];
  int t=threadIdx.x;
  int v = (t<nb)? bsums[t] : 0;
  lds[t]=v; __syncthreads();
  for(int o=1;o<256;o<<=1){ int u=0; if(t>=o) u=lds[t-o]; __syncthreads(); lds[t]+=u; __syncthreads(); }
  if(t<nb) bsums[t]=lds[t]-v;
}
__global__ void scan_p3(const int* __restrict__ in, int* __restrict__ out, const int* pN, int Ns,
                        const int* __restrict__ bsums, int* total){
  __shared__ int tsum[256];
  int n = getE(pN,Ns);
  int base = blockIdx.x*SCH + threadIdx.x*16;
  int v[16]; int s=0;
  #pragma unroll
  for(int q=0;q<16;q++){ int i=base+q; int xv=(i<n)? in[i]:0; v[q]=s; s+=xv; }
  tsum[threadIdx.x]=s; __syncthreads();
  int mine=s;
  for(int o=1;o<256;o<<=1){ int u=0; if(threadIdx.x>=(unsigned)o) u=tsum[threadIdx.x-o]; __syncthreads(); tsum[threadIdx.x]+=u; __syncthreads(); }
  int pre = bsums[blockIdx.x] + tsum[threadIdx.x] - mine;
  #pragma unroll
  for(int q=0;q<16;q++){
    int i=base+q;
    if(i<=n){
      int val = pre+v[q];
      out[i]=val;
      if(i==n && total) *total=val;
    }
  }
}

// ---------------- CSR builders ----------------
__global__ void count_src(const int* __restrict__ es, const int* pE, int Es, int* cnts){
  int e = blockIdx.x*256+threadIdx.x; int E = getE(pE,Es); if(e>=E) return;
  atomicAdd(&cnts[es[e]], 1);
}
__global__ void fill_t2(const int* __restrict__ es, const int* __restrict__ ed, const int* pE, int Es,
                        const int* __restrict__ starts, int* cursor, int* t2){
  int e = blockIdx.x*256+threadIdx.x; int E = getE(pE,Es); if(e>=E) return;
  int s = es[e];
  int p = starts[s] + atomicAdd(&cursor[s],1);
  t2[p] = ed[e];
}
__global__ void fill_eord(const int* __restrict__ ed, const int* pE, int Es,
                          const int* __restrict__ dstarts, int* cursor, int* eord){
  int e = blockIdx.x*256+threadIdx.x; int E = getE(pE,Es); if(e>=E) return;
  int d = ed[e];
  int p = dstarts[d] + atomicAdd(&cursor[d],1);
  eord[p] = e;
}
__global__ void edge_lens_k(const int* __restrict__ ed, const int* pE, int Es,
                            const int* __restrict__ cnts, int* __restrict__ lens){
  int e = blockIdx.x*256+threadIdx.x; int E = getE(pE,Es); if(e>=E) return;
  lens[e] = cnts[ed[e]];
}
__global__ void loop_csr_f(const int* __restrict__ es, const int* __restrict__ eord,
                           const int* __restrict__ dstarts, const float* __restrict__ pos,
                           float* __restrict__ loopat, int N)
{
  int d = blockIdx.x*256+threadIdx.x; if(d>=N) return;
  int r0=dstarts[d], r1=dstarts[d+1];
  float pd0=pos[d*3], pd1=pos[d*3+1], pd2=pos[d*3+2];
  float l0=0,l1=0,l2=0;
  for(int j=r0;j<r1;j++){
    int s = es[eord[j]];
    l0 += pd0-pos[s*3]; l1 += pd1-pos[s*3+1]; l2 += pd2-pos[s*3+2];
  }
  float inv = 1.f/fmaxf((float)(r1-r0), 1.f);
  loopat[d*3+0]=l0*inv; loopat[d*3+1]=l1*inv; loopat[d*3+2]=l2*inv;
}

// ---------------- feature GATv2 (fp32) ----------------
__global__ void feat_logits(const int* __restrict__ es, const int* __restrict__ ed, const int* pE, int Es, int N,
    const float* __restrict__ A, const float* __restrict__ B, const float* __restrict__ pos,
    const float* __restrict__ We, const float* __restrict__ att, const float* __restrict__ loopat,
    float* __restrict__ zb)
{
  int gid = blockIdx.x*blockDim.x + threadIdx.x;
  int w = gid>>6, lane = gid&63;
  int E = getE(pE,Es);
  if(w >= E+N) return;
  int s,d; float e0,e1,e2;
  if(w<E){ s=es[w]; d=ed[w]; e0=pos[d*3]-pos[s*3]; e1=pos[d*3+1]-pos[s*3+1]; e2=pos[d*3+2]-pos[s*3+2]; }
  else   { int n=w-E; s=n; d=n; e0=loopat[n*3]; e1=loopat[n*3+1]; e2=loopat[n*3+2]; }
  int c=lane, c2=lane+64;
  float m1 = A[(size_t)s*128+c ] + B[(size_t)d*128+c ] + e0*We[c ] + e1*We[128+c ] + e2*We[256+c ];
  float m2 = A[(size_t)s*128+c2] + B[(size_t)d*128+c2] + e0*We[c2] + e1*We[128+c2] + e2*We[256+c2];
  float p = leakyf(m1)*att[c] + leakyf(m2)*att[c2];
  for(int off=32; off; off>>=1) p += __shfl_down(p, off, 64);
  if(lane==0) zb[w]=p;
}

__global__ void feat_acc_csr(const int* __restrict__ es, const int* __restrict__ eord,
                             const int* __restrict__ dstarts, const int* pE, int Es,
                             const float* __restrict__ A, const float* __restrict__ zb,
                             const float* __restrict__ bias, float* __restrict__ h, int N)
{
  int w = (blockIdx.x*256+threadIdx.x)>>6;
  int lane = threadIdx.x&63;
  if(w>=N) return;
  int E = getE(pE,Es);
  int r0=dstarts[w], r1=dstarts[w+1];
  float mx = zb[E+w];
  for(int j=r0+lane; j<r1; j+=64) mx = fmaxf(mx, zb[eord[j]]);
  for(int o=32;o;o>>=1) mx = fmaxf(mx, __shfl_down(mx,o,64));
  mx = __shfl(mx, 0, 64);
  float denom = 0.f;
  float2 acc; acc.x=0.f; acc.y=0.f;
  for(int j=r0;j<r1;j++){
    int e = eord[j]; int s = es[e];
    float z = expf(zb[e]-mx);
    denom += z;
    float2 v = *(const float2*)(A + (size_t)s*128 + lane*2);
    acc.x += z*v.x; acc.y += z*v.y;
  }
  {
    float z = expf(zb[E+w]-mx);
    denom += z;
    float2 v = *(const float2*)(A + (size_t)w*128 + lane*2);
    acc.x += z*v.x; acc.y += z*v.y;
  }
  float inv = 1.f/denom;
  float2 bb = *(const float2*)(bias + lane*2);
  acc.x = eluf(acc.x*inv + bb.x); acc.y = eluf(acc.y*inv + bb.y);
  *(float2*)(h + (size_t)w*128 + lane*2) = acc;
}

// ---------------- score GATv2 (fp64) ----------------
__global__ void gemm_score(const float* __restrict__ h, const float* __restrict__ pos,
                           const float* __restrict__ pWl, const float* __restrict__ pWr,
                           double* __restrict__ xls, double* __restrict__ xrs, int N)
{
  int n = blockIdx.x*256+threadIdx.x; if(n>=N) return;
  double sl=0, sr=0;
  for(int k=0;k<128;k++){ double f=h[(size_t)n*128+k]; sl+=f*(double)pWl[k]; sr+=f*(double)pWr[k]; }
  for(int d=0;d<3;d++){ double f=pos[n*3+d]; sl+=f*(double)pWl[128+d]; sr+=f*(double)pWr[128+d]; }
  xls[n]=sl; xrs[n]=sr;
}

// ---------------- candidate enumeration (hash-free augment) ----------------
__global__ void cand1(const int* __restrict__ es, const int* __restrict__ ed, const int* pE, int Es,
                      ull* __restrict__ cpair, int* __restrict__ ccnt){
  int e = blockIdx.x*256+threadIdx.x; int E = getE(pE,Es); if(e>=E) return;
  int s=es[e], t=ed[e];
  cpair[e] = ((ull)(unsigned)t<<32) | (unsigned)s;
  atomicAdd(&ccnt[t],1);
}
__global__ void cand2(const int* __restrict__ es, const int* __restrict__ ed, const int* pE, int Es,
                      const int* __restrict__ l2scan, const int* __restrict__ pT,
                      const int* __restrict__ starts, const int* __restrict__ t2,
                      ull* __restrict__ cpair, int* __restrict__ ccnt){
  int tid = blockIdx.x*256+threadIdx.x;
  int T = *pT; if(T>FLATMAX) T=FLATMAX;
  if(tid >= T) return;
  int E = getE(pE,Es);
  int lo=0, hi=E;
  while(hi-lo>1){ int mid=(lo+hi)>>1; if(l2scan[mid]<=tid) lo=mid; else hi=mid; }
  int e = lo;
  int j = tid - l2scan[e];
  int s = es[e], t = ed[e];
  int b = t2[starts[t]+j];
  cpair[E+tid] = ((ull)(unsigned)b<<32) | (unsigned)s;
  atomicAdd(&ccnt[b],1);
}
__global__ void cand_fill(const ull* __restrict__ cpair, const int* pE, int Es, const int* __restrict__ pT,
                          const int* __restrict__ cstarts, int* __restrict__ ccur, int* __restrict__ cand){
  int tid = blockIdx.x*256+threadIdx.x;
  int E = getE(pE,Es);
  int T = *pT; if(T>FLATMAX) T=FLATMAX;
  if(tid >= E+T) return;
  ull pr = cpair[tid];
  int b = (int)(pr>>32); int s = (int)(pr & 0xFFFFFFFFu);
  int p = cstarts[b] + atomicAdd(&ccur[b],1);
  cand[p] = s;
}

// fused score GATv2 with in-kernel dedup: one 64-thread block per node
__global__ void score_fused2(const int* __restrict__ cand, const int* __restrict__ cstarts,
                             const float* __restrict__ pos,
                             const double* __restrict__ xls, const double* __restrict__ xrs,
                             const float* __restrict__ pWe, const float* __restrict__ paP,
                             const float* __restrict__ pbP,
                             double* __restrict__ score, int N)
{
  int w = blockIdx.x; if(w>=N) return;
  __shared__ int ls[1024];
  int lane = threadIdx.x;
  int r0=cstarts[w], r1=cstarts[w+1]; int d=r1-r0;
  bool small = (d<=1024);
  if(small){ for(int j=lane;j<d;j+=64) ls[j]=cand[r0+j]; }
  __syncthreads();
  float pd0=pos[w*3], pd1=pos[w*3+1], pd2=pos[w*3+2];
  double w0=(double)pWe[0], w1=(double)pWe[1], w2=(double)pWe[2], pa=(double)paP[0];
  double xrd=xrs[w];
  ull umask=0;
  double mx=-1e300, s0=0,s1=0,s2=0; int ucnt=0;
  int nb=0;
  for(int j=lane; j<d; j+=64, nb++){
    int s = small? ls[j] : cand[r0+j];
    bool uniq = true;
    for(int q=0;q<d;q++){
      int v = small? ls[q] : cand[r0+q];
      if(v==s && q<j) uniq=false;
    }
    if(uniq){
      if(nb<64) umask |= 1ULL<<nb;
      ucnt++;
      double e0=(double)(pd0-pos[s*3]), e1=(double)(pd1-pos[s*3+1]), e2=(double)(pd2-pos[s*3+2]);
      s0+=e0; s1+=e1; s2+=e2;
      double lg = leakyd(xls[s]+xrd + e0*w0+e1*w1+e2*w2) * pa;
      mx = fmax(mx, lg);
    }
  }
  for(int o=32;o;o>>=1){
    mx = fmax(mx, __shfl_down(mx,o,64));
    s0 += __shfl_down(s0,o,64);
    s1 += __shfl_down(s1,o,64);
    s2 += __shfl_down(s2,o,64);
    ucnt += __shfl_down(ucnt,o,64);
  }
  mx=__shfl(mx,0,64); s0=__shfl(s0,0,64); s1=__shfl(s1,0,64); s2=__shfl(s2,0,64); ucnt=__shfl(ucnt,0,64);
  double invd = 1.0/(double)(ucnt>0? ucnt : 1);
  double lg_self = leakyd(xls[w]+xrd + (s0*invd)*w0 + (s1*invd)*w1 + (s2*invd)*w2) * pa;
  mx = fmax(mx, lg_self);
  double den=0, acc=0;
  nb=0;
  for(int j=lane; j<d; j+=64, nb++){
    int s = small? ls[j] : cand[r0+j];
    bool uniq;
    if(small && nb<64) uniq = (umask>>nb)&1ULL;
    else {
      uniq = true;
      for(int q=0;q<d;q++){
        int v = small? ls[q] : cand[r0+q];
        if(v==s && q<j) uniq=false;
      }
    }
    if(uniq){
      double e0=(double)(pd0-pos[s*3]), e1=(double)(pd1-pos[s*3+1]), e2=(double)(pd2-pos[s*3+2]);
      double lg = leakyd(xls[s]+xrd + e0*w0+e1*w1+e2*w2) * pa;
      double z = exp(lg-mx);
      den += z; acc += z*xls[s];
    }
  }
  for(int o=32;o;o>>=1){
    den += __shfl_down(den,o,64);
    acc += __shfl_down(acc,o,64);
  }
  if(lane==0){
    double z = exp(lg_self-mx);
    den += z; acc += z*xls[w];
    score[w] = tanh(acc/den + (double)pbP[0]);
  }
}

// ---------------- top-k: 21-bit prefix select + candidate ranking ----------------
__global__ void enc_scores(const double* __restrict__ score, int N, ull* __restrict__ ek){
  int i = blockIdx.x*256+threadIdx.x; if(i>=N) return;
  ek[i] = encd(score[i]);
}
__global__ void hist21(const ull* __restrict__ ek, int N, int* __restrict__ hist){
  int i = blockIdx.x*256+threadIdx.x; if(i>=N) return;
  atomicAdd(&hist[(int)(ek[i]>>43)], 1);
}
__global__ void part21(const int* __restrict__ hist, int* __restrict__ partial){
  __shared__ int red[256];
  int b = blockIdx.x;
  int s=0;
  for(int i=threadIdx.x;i<1024;i+=256) s += hist[b*1024+i];
  red[threadIdx.x]=s; __syncthreads();
  for(int o=128;o;o>>=1){ if(threadIdx.x<(unsigned)o) red[threadIdx.x]+=red[threadIdx.x+o]; __syncthreads(); }
  if(threadIdx.x==0) partial[b]=red[0];
}
__global__ void findbin2(const int* __restrict__ partial, const int* __restrict__ hist,
                         ull* __restrict__ selT, int k){
  __shared__ int ts[256];
  __shared__ int cstar, rbase;
  int t=threadIdx.x;
  int s8[8]; int mysum=0;
  #pragma unroll
  for(int q=0;q<8;q++){ s8[q]=partial[t*8+q]; mysum+=s8[q]; }
  ts[t]=mysum; __syncthreads();
  for(int o=1;o<256;o<<=1){ int u=(t+o<256)? ts[t+o]:0; __syncthreads(); ts[t]+=u; __syncthreads(); }
  int after = (t<255)? ts[t+1] : 0;
  if(ts[t] >= k && after < k){
    int run = after;
    for(int q=7;q>=0;q--){
      if(run < k && run + s8[q] >= k){ cstar = t*8+q; rbase = run; }
      run += s8[q];
    }
  }
  __syncthreads();
  int cs=cstar, rb=rbase;
  int b4[4]; int ms=0;
  #pragma unroll
  for(int q=0;q<4;q++){ b4[q]=hist[cs*1024 + t*4 + q]; ms+=b4[q]; }
  ts[t]=ms; __syncthreads();
  for(int o=1;o<256;o<<=1){ int u=(t+o<256)? ts[t+o]:0; __syncthreads(); ts[t]+=u; __syncthreads(); }
  int after2 = (t<255)? ts[t+1] : 0;
  if(rb+ts[t] >= k && rb+after2 < k){
    int run = rb+after2;
    for(int q=3;q>=0;q--){
      if(run < k && run + b4[q] >= k){ *selT = ((ull)(cs*1024 + t*4 + q)) << 43; }
      run += b4[q];
    }
  }
}
__global__ void compact_k(const ull* __restrict__ ek, int N, const ull* __restrict__ selT,
                          ull* __restrict__ ckey, int* __restrict__ cidx, int* pM){
  int i = blockIdx.x*256+threadIdx.x; if(i>=N) return;
  ull key = ek[i];
  if(key >= *selT){
    int p = reserve_slot(pM);
    ckey[p]=key; cidx[p]=i;
  }
}
__global__ void zerocand_k(const int* __restrict__ cidx, const int* pM, int* __restrict__ rank){
  int i = blockIdx.x*256+threadIdx.x; if(i>=*pM) return;
  rank[cidx[i]] = 0;
}
__global__ void rank_cand(const ull* __restrict__ ckey, const int* __restrict__ cidx, const int* pM,
                          int jlen, int* __restrict__ rank){
  __shared__ ull tk[1024];
  __shared__ int ti[1024];
  int M = *pM;
  if(blockIdx.x*256 >= M) return;
  int i = blockIdx.x*256+threadIdx.x;
  ull ki = 0; int ii = 0x7FFFFFFF;
  if(i<M){ ki=ckey[i]; ii=cidx[i]; }
  int jbeg = blockIdx.y*jlen;
  int jend = jbeg+jlen; if(jend>M) jend=M;
  int c0=0,c1=0,c2=0,c3=0;
  for(int bb=jbeg; bb<jend; bb+=1024){
    for(int j=threadIdx.x; j<1024; j+=256){
      int idx=bb+j;
      tk[j] = (idx<jend)? ckey[idx] : 0ULL;
      ti[j] = (idx<jend)? cidx[idx] : 0x7FFFFFFF;
    }
    __syncthreads();
    #pragma unroll 4
    for(int j=0;j<1024;j+=4){
      ull s0=tk[j],s1=tk[j+1],s2=tk[j+2],s3=tk[j+3];
      int a0=ti[j],a1=ti[j+1],a2=ti[j+2],a3=ti[j+3];
      c0 += (s0>ki)||(s0==ki && a0<ii);
      c1 += (s1>ki)||(s1==ki && a1<ii);
      c2 += (s2>ki)||(s2==ki && a2<ii);
      c3 += (s3>ki)||(s3==ki && a3<ii);
    }
    __syncthreads();
  }
  if(i<M){ int c=(c0+c1)+(c2+c3); if(c) atomicAdd(&rank[ii], c); }
}
__global__ void scatter_perm(const int* __restrict__ rank, int N, int k, int* __restrict__ perm){
  int i = blockIdx.x*256+threadIdx.x; if(i>=N) return;
  int r = rank[i]; if(r<k) perm[r]=i;
}
__global__ void pool_gather(const float* __restrict__ h, const double* __restrict__ score,
                            const int* __restrict__ perm, int k, float* __restrict__ outA){
  int idx = blockIdx.x*256+threadIdx.x; if(idx>=k*32) return;
  int r = idx>>5, g = (idx&31)*4;
  int p = perm[r]; float sc = (float)score[p];
  const float4 x = *(const float4*)(h + (size_t)p*128 + g);
  float4 o; o.x=x.x*sc; o.y=x.y*sc; o.z=x.z*sc; o.w=x.w*sc;
  *(float4*)(outA + (size_t)r*128 + g) = o;
}
__global__ void pos_gather(const float* __restrict__ posc, const int* __restrict__ perm, int k, float* __restrict__ posn){
  int idx = blockIdx.x*256+threadIdx.x; if(idx>=k*3) return;
  int r = idx/3, j = idx-r*3;
  posn[idx] = posc[perm[r]*3+j];
}

// ---------------- filter_adj ----------------
__global__ void filter_flags(const int* __restrict__ es, const int* __restrict__ ed, const int* pE, int Es,
                             const int* __restrict__ rank, int k, int* __restrict__ flags){
  int e = blockIdx.x*256+threadIdx.x; int E = getE(pE,Es); if(e>=E) return;
  flags[e] = (rank[es[e]]<k && rank[ed[e]]<k) ? 1 : 0;
}
__global__ void filter_write(const int* __restrict__ es, const int* __restrict__ ed, const int* pE, int Es,
                             const int* __restrict__ rank, int k, const int* __restrict__ scanout,
                             int* __restrict__ ns, int* __restrict__ nd){
  int e = blockIdx.x*256+threadIdx.x; int E = getE(pE,Es); if(e>=E) return;
  int rs = rank[es[e]], rd = rank[ed[e]];
  if(rs<k && rd<k){ int p = scanout[e]; ns[p]=rs; nd[p]=rd; }
}

// ---------------- output emit ----------------
__global__ void calc_offsets(const int* __restrict__ cnt, long long* __restrict__ offs){
  if(blockIdx.x==0 && threadIdx.x==0){
    long long E1 = cnt[C_E1], E2 = cnt[C_E2];
    long long o = (long long)KK2*128;
    offs[0]=0;
    offs[1]=o; o += 2*E2;
    offs[2]=o; o += 2*E1;
    offs[3]=o; o += 2*(long long)EE0;
    offs[4]=o; o += (long long)KK2*3;
    offs[5]=o; o += (long long)KK1*3;
    offs[6]=o; o += (long long)NN0*3;
    offs[7]=o; o += 3*E2;
    offs[8]=o; o += 3*E1;
    offs[9]=o;
  }
}
__global__ void emit_pe(const int* __restrict__ s, const int* __restrict__ d, const int* pE, int Es,
                        const long long* __restrict__ offs, int oi, float* __restrict__ out){
  int e = blockIdx.x*256+threadIdx.x; int E = getE(pE,Es); if(e>=E) return;
  long long o = offs[oi];
  out[o+e]   = (float)s[e];
  out[o+E+e] = (float)d[e];
}
__global__ void emit_pp(const float* __restrict__ p, int n, const long long* __restrict__ offs, int oi, float* __restrict__ out){
  int i = blockIdx.x*256+threadIdx.x; if(i>=n) return;
  out[offs[oi]+i] = p[i];
}
__global__ void emit_eas(const int* __restrict__ s, const int* __restrict__ d, const int* pE, int Es,
                         const float* __restrict__ pos, const long long* __restrict__ offs, int oi, float* __restrict__ out){
  int e = blockIdx.x*256+threadIdx.x; int E = getE(pE,Es); if(e>=E) return;
  long long o = offs[oi];
  int ss=s[e], dd=d[e];
  out[o+3*e+0] = pos[dd*3+0]-pos[ss*3+0];
  out[o+3*e+1] = pos[dd*3+1]-pos[ss*3+1];
  out[o+3*e+2] = pos[dd*3+2]-pos[ss*3+2];
}

// =======================================================================
extern "C" void kernel_launch(void* const* d_in, const int* in_sizes, int n_in,
                              void* d_out, int out_size, void* d_ws, size_t ws_size,
                              hipStream_t stream)
{
  const float* x    = (const float*)d_in[0];
  const float* yv   = (const float*)d_in[1];
  const float* pos0 = (const float*)d_in[2];
  const int*   ei   = (const int*)d_in[3];
  const float* Wl0  = (const float*)d_in[4];
  const float* Wr0  = (const float*)d_in[5];
  const float* We0  = (const float*)d_in[6];
  const float* a0   = (const float*)d_in[7];
  const float* b0   = (const float*)d_in[8];
  const float* Wls  = (const float*)d_in[9];
  const float* Wrs  = (const float*)d_in[10];
  const float* Wes  = (const float*)d_in[11];
  const float* atts = (const float*)d_in[12];
  const float* bs   = (const float*)d_in[13];
  const float* pWl  = (const float*)d_in[14];
  const float* pWr  = (const float*)d_in[15];
  const float* pWe  = (const float*)d_in[16];
  const float* pa   = (const float*)d_in[17];
  const float* pb   = (const float*)d_in[18];
  const float* linW = (const float*)d_in[19];
  const float* linb = (const float*)d_in[20];
  float* out = (float*)d_out;

  const int* eisrc = ei;
  const int* eidst = ei + EE0;

  char* base = (char*)d_ws; size_t off = 0;
  auto alloc = [&](size_t b)->void*{
    off = (off + 255) & ~(size_t)255;
    void* p = base + off; off += b; return p;
  };
  int*       cnt     = (int*)alloc(64*4);
  long long* offs    = (long long*)alloc(16*8);
  int*       bsums   = (int*)alloc(256*4);
  ull*       sel     = (ull*)alloc(2*8);
  int*       hist    = (int*)alloc((size_t)HBINS*4);
  int*       partial = (int*)alloc(2048*4);
  double*    xls     = (double*)alloc((size_t)NN0*8);
  double*    xrs     = (double*)alloc((size_t)NN0*8);
  double*    score   = (double*)alloc((size_t)NN0*8);
  ull*       ek      = (ull*)alloc((size_t)NN0*8);
  ull*       ckey    = (ull*)alloc((size_t)NN0*8);
  int*       cidx    = (int*)alloc((size_t)NN0*4);
  float*     loopatF = (float*)alloc((size_t)NN0*12);
  int*       rank    = (int*)alloc((size_t)NN0*4);
  int*       perm    = (int*)alloc((size_t)NN0*4);
  int*       cntsrc  = (int*)alloc((size_t)NN0*4);
  int*       starts  = (int*)alloc((size_t)(NN0+1)*4);
  int*       cursor  = (int*)alloc((size_t)NN0*4);
  int*       ccnt    = (int*)alloc((size_t)NN0*4);
  int*       dstarts = (int*)alloc((size_t)(NN0+1)*4);
  int*       cstarts = (int*)alloc((size_t)(NN0+1)*4);
  int*       eord    = (int*)alloc((size_t)EE0*4);
  int*       lens    = (int*)alloc((size_t)EE0*4);
  int*       l2scan  = (int*)alloc((size_t)(EE0+1)*4);
  int*       t2      = (int*)alloc((size_t)EE0*4);
  int*       flags   = (int*)alloc((size_t)EE0*4);
  int*       scanout = (int*)alloc((size_t)(EE0+1)*4);
  int*       eb0s    = (int*)alloc((size_t)EE0*4);
  int*       eb0d    = (int*)alloc((size_t)EE0*4);
  int*       eb1s    = (int*)alloc((size_t)EE0*4);
  int*       eb1d    = (int*)alloc((size_t)EE0*4);
  float*     pos1    = (float*)alloc((size_t)KK1*12);
  float*     pos2    = (float*)alloc((size_t)KK2*12);
  float*     A       = (float*)alloc((size_t)NN0*128*4);
  float*     B       = (float*)alloc((size_t)NN0*128*4);
  float*     h       = (float*)alloc((size_t)NN0*128*4);
  void*      uni     = alloc((size_t)(EE0+FLATMAX)*8);   // union: cpair (pool) / zbF (conv)
  if(off > ws_size) return;

  int*    cand  = (int*)B;       // dead during pool stage; see Round-5 alias note
  float*  zbF   = (float*)uni;
  ull*    cpair = (ull*)uni;
  ull*    selT  = sel;

  hipMemsetAsync(cnt, 0, 64*4, stream);

  auto scan = [&](const int* in, int* sout, const int* pN, int Ns, int* total){
    int nb = CDIV(Ns+1, SCH);
    scan_p1<<<nb,256,0,stream>>>(in,pN,Ns,bsums);
    scan_p2<<<1,256,0,stream>>>(bsums,nb);
    scan_p3<<<nb,256,0,stream>>>(in,sout,pN,Ns,bsums,total);
  };

  auto build_csr_dst = [&](const int* es, const int* ed, const int* pE, int Emax, int N, const float* pcur){
    hipMemsetAsync(ccnt,0,(size_t)N*4,stream);
    count_src<<<CDIV(Emax,256),256,0,stream>>>(ed,pE,Emax,ccnt);
    scan(ccnt,dstarts,nullptr,N,nullptr);
    hipMemsetAsync(cursor,0,(size_t)N*4,stream);
    fill_eord<<<CDIV(Emax,256),256,0,stream>>>(ed,pE,Emax,dstarts,cursor,eord);
    loop_csr_f<<<CDIV(N,256),256,0,stream>>>(es,eord,dstarts,pcur,loopatF,N);
  };

  auto feat_conv = [&](const float* Wl, const float* Wr, const float* We, const float* att, const float* bias,
                       const int* es, const int* ed, const int* pE, int Emax, int N, const float* pcur,
                       bool conv0mode){
    if(conv0mode)
      gemm_k<0,true><<<CDIV(N,8),256,0,stream>>>(x,pcur,yv,Wl,Wr,nullptr,A,B,N);
    else
      gemm_k<1,true><<<CDIV(N,8),256,0,stream>>>(h,pcur,nullptr,Wl,Wr,nullptr,A,B,N);
    long long wt = (long long)(Emax+N)*64;
    feat_logits<<<(int)CDIV(wt,256),256,0,stream>>>(es,ed,pE,Emax,N,A,B,pcur,We,att,loopatF,zbF);
    feat_acc_csr<<<CDIV(N*64,256),256,0,stream>>>(es,eord,dstarts,pE,Emax,A,zbF,bias,h,N);
  };

  auto pool = [&](int l, int N, int k, const int* es, const int* ed, const int* pE, int Emax,
                  const float* pcur, float* pnext, int* ns, int* nd, int eslot, int cmslot){
    // src-CSR for 2-hop enumeration
    hipMemsetAsync(cntsrc, 0, (size_t)N*4, stream);
    count_src<<<CDIV(Emax,256),256,0,stream>>>(es,pE,Emax,cntsrc);
    scan(cntsrc,starts,nullptr,N,nullptr);
    hipMemsetAsync(cursor, 0, (size_t)N*4, stream);
    fill_t2<<<CDIV(Emax,256),256,0,stream>>>(es,ed,pE,Emax,starts,cursor,t2);
    edge_lens_k<<<CDIV(Emax,256),256,0,stream>>>(ed,pE,Emax,cntsrc,lens);
    scan(lens,l2scan,pE,Emax,cnt+C_T2);
    // candidate pairs (1-hop + 2-hop, dups kept), bucketed by dst
    hipMemsetAsync(ccnt, 0, (size_t)N*4, stream);
    cand1<<<CDIV(Emax,256),256,0,stream>>>(es,ed,pE,Emax,cpair,ccnt);
    cand2<<<CDIV(FLATMAX,256),256,0,stream>>>(es,ed,pE,Emax,l2scan,cnt+C_T2,starts,t2,cpair,ccnt);
    scan(ccnt,cstarts,nullptr,N,nullptr);
    hipMemsetAsync(cursor,0,(size_t)N*4,stream);
    cand_fill<<<CDIV(EE0+FLATMAX,256),256,0,stream>>>(cpair,pE,Emax,cnt+C_T2,cstarts,cursor,cand);
    // fused score GATv2 (fp64) with in-kernel dedup
    gemm_score<<<CDIV(N,256),256,0,stream>>>(h,pcur,pWl+l*131,pWr+l*131,xls,xrs,N);
    score_fused2<<<N,64,0,stream>>>(cand,cstarts,pcur,xls,xrs,pWe+l*3,pa+l,pb+l,score,N);
    // top-k: 1-round 21-bit prefix select + rank among candidates
    enc_scores<<<CDIV(N,256),256,0,stream>>>(score,N,ek);
    hipMemsetAsync(hist,0,(size_t)HBINS*4,stream);
    hist21<<<CDIV(N,256),256,0,stream>>>(ek,N,hist);
    part21<<<2048,256,0,stream>>>(hist,partial);
    findbin2<<<1,256,0,stream>>>(partial,hist,selT,k);
    compact_k<<<CDIV(N,256),256,0,stream>>>(ek,N,selT,ckey,cidx,cnt+cmslot);
    hipMemsetAsync(rank,0x3f,(size_t)N*4,stream);
    zerocand_k<<<CDIV(N,256),256,0,stream>>>(cidx,cnt+cmslot,rank);
    {
      int jch = 8, jlen = CDIV(N,jch);
      dim3 g(CDIV(N,256), jch);
      rank_cand<<<g,256,0,stream>>>(ckey,cidx,cnt+cmslot,jlen,rank);
    }
    scatter_perm<<<CDIV(N,256),256,0,stream>>>(rank,N,k,perm);
    pool_gather<<<CDIV(k*32,256),256,0,stream>>>(h,score,perm,k,A);
    hipMemcpyAsync(h,A,(size_t)k*128*4,hipMemcpyDeviceToDevice,stream);
    pos_gather<<<CDIV(k*3,256),256,0,stream>>>(pcur,perm,k,pnext);
    filter_flags<<<CDIV(Emax,256),256,0,stream>>>(es,ed,pE,Emax,rank,k,flags);
    scan(flags,scanout,pE,Emax,cnt+eslot);
    filter_write<<<CDIV(Emax,256),256,0,stream>>>(es,ed,pE,Emax,rank,k,scanout,ns,nd);
  };

  // ================= pipeline =================
  build_csr_dst(eisrc,eidst,nullptr,EE0, NN0, pos0);
  feat_conv(Wl0,Wr0,We0,a0,b0, eisrc,eidst,nullptr,EE0, NN0, pos0, true);
  feat_conv(Wls+0*16768,Wrs+0*16768,Wes+0*384,atts+0*128,bs+0*128, eisrc,eidst,nullptr,EE0, NN0, pos0, false);
  pool(0, NN0, KK1, eisrc,eidst,nullptr,EE0, pos0,pos1, eb0s,eb0d, C_E1, C_M0);
  build_csr_dst(eb0s,eb0d,cnt+C_E1,EE0, KK1, pos1);
  feat_conv(Wls+1*16768,Wrs+1*16768,Wes+1*384,atts+1*128,bs+1*128, eb0s,eb0d,cnt+C_E1,EE0, KK1, pos1, false);
  pool(1, KK1, KK2, eb0s,eb0d,cnt+C_E1,EE0, pos1,pos2, eb1s,eb1d, C_E2, C_M1);
  build_csr_dst(eb1s,eb1d,cnt+C_E2,EE0, KK2, pos2);
  feat_conv(Wls+2*16768,Wrs+2*16768,Wes+2*384,atts+2*128,bs+2*128, eb1s,eb1d,cnt+C_E2,EE0, KK2, pos2, false);
  feat_conv(Wls+3*16768,Wrs+3*16768,Wes+3*384,atts+3*128,bs+3*128, eb1s,eb1d,cnt+C_E2,EE0, KK2, pos2, false);
  gemm_k<2,false><<<CDIV(KK2,8),256,0,stream>>>(h,nullptr,nullptr,linW,nullptr,linb,out,nullptr,KK2);

  calc_offsets<<<1,32,0,stream>>>(cnt,offs);
  emit_pe <<<CDIV(EE0,256),256,0,stream>>>(eb1s,eb1d,cnt+C_E2,EE0,offs,1,out);
  emit_pe <<<CDIV(EE0,256),256,0,stream>>>(eb0s,eb0d,cnt+C_E1,EE0,offs,2,out);
  emit_pe <<<CDIV(EE0,256),256,0,stream>>>(eisrc,eidst,nullptr,EE0,offs,3,out);
  emit_pp <<<CDIV(KK2*3,256),256,0,stream>>>(pos2,KK2*3,offs,4,out);
  emit_pp <<<CDIV(KK1*3,256),256,0,stream>>>(pos1,KK1*3,offs,5,out);
  emit_pp <<<CDIV(NN0*3,256),256,0,stream>>>(pos0,NN0*3,offs,6,out);
  emit_eas<<<CDIV(EE0,256),256,0,stream>>>(eb1s,eb1d,cnt+C_E2,EE0,pos2,offs,7,out);
  emit_eas<<<CDIV(EE0,256),256,0,stream>>>(eb0s,eb0d,cnt+C_E1,EE0,pos1,offs,8,out);
  emit_eas<<<CDIV(EE0,256),256,0,stream>>>(eisrc,eidst,nullptr,EE0,pos0,offs,9,out);
}

// Round 8
// 3263.282 us; speedup vs baseline: 1.4357x; 1.0530x over previous
//
#include <hip/hip_runtime.h>

typedef unsigned long long ull;

#define NN0 80000
#define EE0 480000
#define KK1 40000
#define KK2 20000
#define FLATMAX 8000000
#define SCH 4096
#define CDIV(a,b) (((a)+(b)-1)/(b))
#define HBINS (1<<21)

// counter slots
#define C_E1 2
#define C_E2 3
#define C_T2 4
#define C_M0 5
#define C_M1 6

__device__ __forceinline__ int getE(const int* p, int s){ if(!p) return s; int e=*p; return e<s? e : s; }
__device__ __forceinline__ float leakyf(float x){ return x>0.f? x : 0.2f*x; }
__device__ __forceinline__ double leakyd(double x){ return x>0.0? x : 0.2*x; }
__device__ __forceinline__ float eluf(float x){ return x>0.f? x : (expf(x)-1.f); }

__device__ __forceinline__ ull encd(double f){ ull u=(ull)__double_as_longlong(f); return (u>>63)? ~u : (u|0x8000000000000000ULL); }

__device__ __forceinline__ int reserve_slot(int* ctr){
  ull mask = __ballot(1);
  int lane = threadIdx.x & 63;
  int lead = __ffsll((long long)mask) - 1;
  int base = 0;
  if(lane==lead) base = atomicAdd(ctr, (int)__popcll(mask));
  base = __shfl(base, lead, 64);
  return base + (int)__popcll(mask & ((1ULL<<lane)-1ULL));
}

// ---------------- GEMM: xl/xr projections ----------------
template<int MODE, bool DUAL>
__global__ void gemm_k(const float* __restrict__ F1, const float* __restrict__ pos,
                       const float* __restrict__ yv,
                       const float* __restrict__ W1, const float* __restrict__ W2,
                       const float* __restrict__ bias,
                       float* __restrict__ O1, float* __restrict__ O2, int N)
{
  int t = threadIdx.x;
  int row = blockIdx.x*8 + (t>>5);
  int g = (t&31)*4;
  if(row>=N) return;
  const int K = MODE==0? 11 : (MODE==1? 131 : 128);
  float a0=0,a1=0,a2=0,a3=0,b0=0,b1=0,b2=0,b3=0;
  for(int k=0;k<K;k++){
    float f;
    if(MODE==0)      f = (k<5)? F1[row*5+k] : (k<8? pos[row*3+(k-5)] : yv[0]);
    else if(MODE==1) f = (k<128)? F1[(size_t)row*128+k] : pos[row*3+(k-128)];
    else             f = F1[(size_t)row*128+k];
    float4 w = *(const float4*)(W1 + (size_t)k*128 + g);
    a0 += f*w.x; a1 += f*w.y; a2 += f*w.z; a3 += f*w.w;
    if(DUAL){
      float4 v = *(const float4*)(W2 + (size_t)k*128 + g);
      b0 += f*v.x; b1 += f*v.y; b2 += f*v.z; b3 += f*v.w;
    }
  }
  if(bias){ a0+=bias[g]; a1+=bias[g+1]; a2+=bias[g+2]; a3+=bias[g+3]; }
  float4 r; r.x=a0; r.y=a1; r.z=a2; r.w=a3;
  *(float4*)(O1+(size_t)row*128+g) = r;
  if(DUAL){ float4 r2; r2.x=b0; r2.y=b1; r2.z=b2; r2.w=b3; *(float4*)(O2+(size_t)row*128+g) = r2; }
}

// ---------------- multi-block exclusive scan ----------------
__global__ void scan_p1(const int* __restrict__ in, const int* pN, int Ns, int* __restrict__ bsums){
  __shared__ int red[256];
  int n = getE(pN,Ns);
  int base = blockIdx.x*SCH;
  int s=0;
  for(int i=base+threadIdx.x; i<base+SCH; i+=256) if(i<n) s+=in[i];
  red[threadIdx.x]=s; __syncthreads();
  for(int o=128;o;o>>=1){ if(threadIdx.x<(unsigned)o) red[threadIdx.x]+=red[threadIdx.x+o]; __syncthreads(); }
  if(threadIdx.x==0) bsums[blockIdx.x]=red[0];
}
__global__ void scan_p2(int* bsums, int nb){
  __shared__ int lds[256];
  int t=threadIdx.x;
  int v = (t<nb)? bsums[t] : 0;
  lds[t]=v; __syncthreads();
  for(int o=1;o<256;o<<=1){ int u=0; if(t>=o) u=lds[t-o]; __syncthreads(); lds[t]+=u; __syncthreads(); }
  if(t<nb) bsums[t]=lds[t]-v;
}
__global__ void scan_p3(const int* __restrict__ in, int* __restrict__ out, const int* pN, int Ns,
                        const int* __restrict__ bsums, int* total){
  __shared__ int tsum[256];
  int n = getE(pN,Ns);
  int base = blockIdx.x*SCH + threadIdx.x*16;
  int v[16]; int s=0;
  #pragma unroll
  for(int q=0;q<16;q++){ int i=base+q; int xv=(i<n)? in[i]:0; v[q]=s; s+=xv; }
  tsum[threadIdx.x]=s; __syncthreads();
  int mine=s;
  for(int o=1;o<256;o<<=1){ int u=0; if(threadIdx.x>=(unsigned)o) u=tsum[threadIdx.x-o]; __syncthreads(); tsum[threadIdx.x]+=u; __syncthreads(); }
  int pre = bsums[blockIdx.x] + tsum[threadIdx.x] - mine;
  #pragma unroll
  for(int q=0;q<16;q++){
    int i=base+q;
    if(i<=n){
      int val = pre+v[q];
      out[i]=val;
      if(i==n && total) *total=val;
    }
  }
}

// ---------------- CSR builders ----------------
__global__ void count_src(const int* __restrict__ es, const int* pE, int Es, int* cnts){
  int e = blockIdx.x*256+threadIdx.x; int E = getE(pE,Es); if(e>=E) return;
  atomicAdd(&cnts[es[e]], 1);
}
__global__ void fill_t2(const int* __restrict__ es, const int* __restrict__ ed, const int* pE, int Es,
                        const int* __restrict__ starts, int* cursor, int* t2){
  int e = blockIdx.x*256+threadIdx.x; int E = getE(pE,Es); if(e>=E) return;
  int s = es[e];
  int p = starts[s] + atomicAdd(&cursor[s],1);
  t2[p] = ed[e];
}
__global__ void fill_eord(const int* __restrict__ ed, const int* pE, int Es,
                          const int* __restrict__ dstarts, int* cursor, int* eord){
  int e = blockIdx.x*256+threadIdx.x; int E = getE(pE,Es); if(e>=E) return;
  int d = ed[e];
  int p = dstarts[d] + atomicAdd(&cursor[d],1);
  eord[p] = e;
}
__global__ void edge_lens_k(const int* __restrict__ ed, const int* pE, int Es,
                            const int* __restrict__ cnts, int* __restrict__ lens){
  int e = blockIdx.x*256+threadIdx.x; int E = getE(pE,Es); if(e>=E) return;
  lens[e] = cnts[ed[e]];
}
__global__ void loop_csr_f(const int* __restrict__ es, const int* __restrict__ eord,
                           const int* __restrict__ dstarts, const float* __restrict__ pos,
                           float* __restrict__ loopat, int N)
{
  int d = blockIdx.x*256+threadIdx.x; if(d>=N) return;
  int r0=dstarts[d], r1=dstarts[d+1];
  float pd0=pos[d*3], pd1=pos[d*3+1], pd2=pos[d*3+2];
  float l0=0,l1=0,l2=0;
  for(int j=r0;j<r1;j++){
    int s = es[eord[j]];
    l0 += pd0-pos[s*3]; l1 += pd1-pos[s*3+1]; l2 += pd2-pos[s*3+2];
  }
  float inv = 1.f/fmaxf((float)(r1-r0), 1.f);
  loopat[d*3+0]=l0*inv; loopat[d*3+1]=l1*inv; loopat[d*3+2]=l2*inv;
}

// ---------------- feature GATv2 (fp32) ----------------
__global__ void feat_logits(const int* __restrict__ es, const int* __restrict__ ed, const int* pE, int Es, int N,
    const float* __restrict__ A, const float* __restrict__ B, const float* __restrict__ pos,
    const float* __restrict__ We, const float* __restrict__ att, const float* __restrict__ loopat,
    float* __restrict__ zb)
{
  int gid = blockIdx.x*blockDim.x + threadIdx.x;
  int w = gid>>6, lane = gid&63;
  int E = getE(pE,Es);
  if(w >= E+N) return;
  int s,d; float e0,e1,e2;
  if(w<E){ s=es[w]; d=ed[w]; e0=pos[d*3]-pos[s*3]; e1=pos[d*3+1]-pos[s*3+1]; e2=pos[d*3+2]-pos[s*3+2]; }
  else   { int n=w-E; s=n; d=n; e0=loopat[n*3]; e1=loopat[n*3+1]; e2=loopat[n*3+2]; }
  int c=lane, c2=lane+64;
  float m1 = A[(size_t)s*128+c ] + B[(size_t)d*128+c ] + e0*We[c ] + e1*We[128+c ] + e2*We[256+c ];
  float m2 = A[(size_t)s*128+c2] + B[(size_t)d*128+c2] + e0*We[c2] + e1*We[128+c2] + e2*We[256+c2];
  float p = leakyf(m1)*att[c] + leakyf(m2)*att[c2];
  for(int off=32; off; off>>=1) p += __shfl_down(p, off, 64);
  if(lane==0) zb[w]=p;
}

__global__ void feat_acc_csr(const int* __restrict__ es, const int* __restrict__ eord,
                             const int* __restrict__ dstarts, const int* pE, int Es,
                             const float* __restrict__ A, const float* __restrict__ zb,
                             const float* __restrict__ bias, float* __restrict__ h, int N)
{
  int w = (blockIdx.x*256+threadIdx.x)>>6;
  int lane = threadIdx.x&63;
  if(w>=N) return;
  int E = getE(pE,Es);
  int r0=dstarts[w], r1=dstarts[w+1];
  float mx = zb[E+w];
  for(int j=r0+lane; j<r1; j+=64) mx = fmaxf(mx, zb[eord[j]]);
  for(int o=32;o;o>>=1) mx = fmaxf(mx, __shfl_down(mx,o,64));
  mx = __shfl(mx, 0, 64);
  float denom = 0.f;
  float2 acc; acc.x=0.f; acc.y=0.f;
  for(int j=r0;j<r1;j++){
    int e = eord[j]; int s = es[e];
    float z = expf(zb[e]-mx);
    denom += z;
    float2 v = *(const float2*)(A + (size_t)s*128 + lane*2);
    acc.x += z*v.x; acc.y += z*v.y;
  }
  {
    float z = expf(zb[E+w]-mx);
    denom += z;
    float2 v = *(const float2*)(A + (size_t)w*128 + lane*2);
    acc.x += z*v.x; acc.y += z*v.y;
  }
  float inv = 1.f/denom;
  float2 bb = *(const float2*)(bias + lane*2);
  acc.x = eluf(acc.x*inv + bb.x); acc.y = eluf(acc.y*inv + bb.y);
  *(float2*)(h + (size_t)w*128 + lane*2) = acc;
}

// ---------------- score GATv2 (fp64) ----------------
__global__ void gemm_score(const float* __restrict__ h, const float* __restrict__ pos,
                           const float* __restrict__ pWl, const float* __restrict__ pWr,
                           double* __restrict__ xls, double* __restrict__ xrs, int N)
{
  int n = blockIdx.x*256+threadIdx.x; if(n>=N) return;
  double sl=0, sr=0;
  for(int k=0;k<128;k++){ double f=h[(size_t)n*128+k]; sl+=f*(double)pWl[k]; sr+=f*(double)pWr[k]; }
  for(int d=0;d<3;d++){ double f=pos[n*3+d]; sl+=f*(double)pWl[128+d]; sr+=f*(double)pWr[128+d]; }
  xls[n]=sl; xrs[n]=sr;
}

// ---------------- candidate enumeration (hash-free augment) ----------------
__global__ void cand1(const int* __restrict__ es, const int* __restrict__ ed, const int* pE, int Es,
                      ull* __restrict__ cpair, int* __restrict__ ccnt){
  int e = blockIdx.x*256+threadIdx.x; int E = getE(pE,Es); if(e>=E) return;
  int s=es[e], t=ed[e];
  cpair[e] = ((ull)(unsigned)t<<32) | (unsigned)s;
  atomicAdd(&ccnt[t],1);
}
__global__ void cand2(const int* __restrict__ es, const int* __restrict__ ed, const int* pE, int Es,
                      const int* __restrict__ l2scan, const int* __restrict__ pT,
                      const int* __restrict__ starts, const int* __restrict__ t2,
                      ull* __restrict__ cpair, int* __restrict__ ccnt){
  int tid = blockIdx.x*256+threadIdx.x;
  int T = *pT; if(T>FLATMAX) T=FLATMAX;
  if(tid >= T) return;
  int E = getE(pE,Es);
  int lo=0, hi=E;
  while(hi-lo>1){ int mid=(lo+hi)>>1; if(l2scan[mid]<=tid) lo=mid; else hi=mid; }
  int e = lo;
  int j = tid - l2scan[e];
  int s = es[e], t = ed[e];
  int b = t2[starts[t]+j];
  cpair[E+tid] = ((ull)(unsigned)b<<32) | (unsigned)s;
  atomicAdd(&ccnt[b],1);
}
__global__ void cand_fill(const ull* __restrict__ cpair, const int* pE, int Es, const int* __restrict__ pT,
                          const int* __restrict__ cstarts, int* __restrict__ ccur, int* __restrict__ cand){
  int tid = blockIdx.x*256+threadIdx.x;
  int E = getE(pE,Es);
  int T = *pT; if(T>FLATMAX) T=FLATMAX;
  if(tid >= E+T) return;
  ull pr = cpair[tid];
  int b = (int)(pr>>32); int s = (int)(pr & 0xFFFFFFFFu);
  int p = cstarts[b] + atomicAdd(&ccur[b],1);
  cand[p] = s;
}

// fused score GATv2 with in-kernel dedup: one 64-thread block per node
__global__ void score_fused2(const int* __restrict__ cand, const int* __restrict__ cstarts,
                             const float* __restrict__ pos,
                             const double* __restrict__ xls, const double* __restrict__ xrs,
                             const float* __restrict__ pWe, const float* __restrict__ paP,
                             const float* __restrict__ pbP,
                             double* __restrict__ score, int N)
{
  int w = blockIdx.x; if(w>=N) return;
  __shared__ int ls[1024];
  int lane = threadIdx.x;
  int r0=cstarts[w], r1=cstarts[w+1]; int d=r1-r0;
  bool small = (d<=1024);
  if(small){ for(int j=lane;j<d;j+=64) ls[j]=cand[r0+j]; }
  __syncthreads();
  float pd0=pos[w*3], pd1=pos[w*3+1], pd2=pos[w*3+2];
  double w0=(double)pWe[0], w1=(double)pWe[1], w2=(double)pWe[2], pa=(double)paP[0];
  double xrd=xrs[w];
  ull umask=0;
  double mx=-1e300, s0=0,s1=0,s2=0; int ucnt=0;
  int nb=0;
  for(int j=lane; j<d; j+=64, nb++){
    int s = small? ls[j] : cand[r0+j];
    bool uniq = true;
    for(int q=0;q<d;q++){
      int v = small? ls[q] : cand[r0+q];
      if(v==s && q<j) uniq=false;
    }
    if(uniq){
      if(nb<64) umask |= 1ULL<<nb;
      ucnt++;
      double e0=(double)(pd0-pos[s*3]), e1=(double)(pd1-pos[s*3+1]), e2=(double)(pd2-pos[s*3+2]);
      s0+=e0; s1+=e1; s2+=e2;
      double lg = leakyd(xls[s]+xrd + e0*w0+e1*w1+e2*w2) * pa;
      mx = fmax(mx, lg);
    }
  }
  for(int o=32;o;o>>=1){
    mx = fmax(mx, __shfl_down(mx,o,64));
    s0 += __shfl_down(s0,o,64);
    s1 += __shfl_down(s1,o,64);
    s2 += __shfl_down(s2,o,64);
    ucnt += __shfl_down(ucnt,o,64);
  }
  mx=__shfl(mx,0,64); s0=__shfl(s0,0,64); s1=__shfl(s1,0,64); s2=__shfl(s2,0,64); ucnt=__shfl(ucnt,0,64);
  double invd = 1.0/(double)(ucnt>0? ucnt : 1);
  double lg_self = leakyd(xls[w]+xrd + (s0*invd)*w0 + (s1*invd)*w1 + (s2*invd)*w2) * pa;
  mx = fmax(mx, lg_self);
  double den=0, acc=0;
  nb=0;
  for(int j=lane; j<d; j+=64, nb++){
    int s = small? ls[j] : cand[r0+j];
    bool uniq;
    if(small && nb<64) uniq = (umask>>nb)&1ULL;
    else {
      uniq = true;
      for(int q=0;q<d;q++){
        int v = small? ls[q] : cand[r0+q];
        if(v==s && q<j) uniq=false;
      }
    }
    if(uniq){
      double e0=(double)(pd0-pos[s*3]), e1=(double)(pd1-pos[s*3+1]), e2=(double)(pd2-pos[s*3+2]);
      double lg = leakyd(xls[s]+xrd + e0*w0+e1*w1+e2*w2) * pa;
      double z = exp(lg-mx);
      den += z; acc += z*xls[s];
    }
  }
  for(int o=32;o;o>>=1){
    den += __shfl_down(den,o,64);
    acc += __shfl_down(acc,o,64);
  }
  if(lane==0){
    double z = exp(lg_self-mx);
    den += z; acc += z*xls[w];
    score[w] = tanh(acc/den + (double)pbP[0]);
  }
}

// ---------------- top-k: 2-round 21-bit refine select + candidate ranking ----------------
__global__ void enc_scores(const double* __restrict__ score, int N, ull* __restrict__ ek,
                           int* __restrict__ rank){
  int i = blockIdx.x*256+threadIdx.x; if(i>=N) return;
  ek[i] = encd(score[i]);
  rank[i] = 0x3f3f3f3f;
}
// histogram of 21-bit digit at `shift`, restricted to keys whose bits above shift+21 match selT
__global__ void hist_g(const ull* __restrict__ ek, int N, int shift, const ull* __restrict__ selT,
                       int* __restrict__ hist){
  int i = blockIdx.x*256+threadIdx.x; if(i>=N) return;
  ull key = ek[i];
  if(shift+21 < 64){
    if((key >> (shift+21)) != ((*selT) >> (shift+21))) return;
  }
  atomicAdd(&hist[(int)((key>>shift)&0x1FFFFF)], 1);
}
__global__ void part21(const int* __restrict__ hist, int* __restrict__ partial){
  __shared__ int red[256];
  int b = blockIdx.x;
  int s=0;
  for(int i=threadIdx.x;i<1024;i+=256) s += hist[b*1024+i];
  red[threadIdx.x]=s; __syncthreads();
  for(int o=128;o;o>>=1){ if(threadIdx.x<(unsigned)o) red[threadIdx.x]+=red[threadIdx.x+o]; __syncthreads(); }
  if(threadIdx.x==0) partial[b]=red[0];
}
// find the bin containing the keff-th largest key; update selT (bin at `shift`) and selRB (count strictly above)
__global__ void findbin_g(const int* __restrict__ partial, const int* __restrict__ hist,
                          ull* __restrict__ selT, int* __restrict__ selRB, int k, int shift){
  __shared__ int ts[256];
  __shared__ int cstar, rbase;
  int t=threadIdx.x;
  int keff = k - *selRB;
  int s8[8]; int mysum=0;
  #pragma unroll
  for(int q=0;q<8;q++){ s8[q]=partial[t*8+q]; mysum+=s8[q]; }
  ts[t]=mysum; __syncthreads();
  for(int o=1;o<256;o<<=1){ int u=(t+o<256)? ts[t+o]:0; __syncthreads(); ts[t]+=u; __syncthreads(); }
  int after = (t<255)? ts[t+1] : 0;
  if(ts[t] >= keff && after < keff){
    int run = after;
    for(int q=7;q>=0;q--){
      if(run < keff && run + s8[q] >= keff){ cstar = t*8+q; rbase = run; }
      run += s8[q];
    }
  }
  __syncthreads();
  int cs=cstar, rb=rbase;
  int b4[4]; int ms=0;
  #pragma unroll
  for(int q=0;q<4;q++){ b4[q]=hist[cs*1024 + t*4 + q]; ms+=b4[q]; }
  ts[t]=ms; __syncthreads();
  for(int o=1;o<256;o<<=1){ int u=(t+o<256)? ts[t+o]:0; __syncthreads(); ts[t]+=u; __syncthreads(); }
  int after2 = (t<255)? ts[t+1] : 0;
  if(rb+ts[t] >= keff && rb+after2 < keff){
    int run = rb+after2;
    for(int q=3;q>=0;q--){
      if(run < keff && run + b4[q] >= keff){
        *selT |= ((ull)(cs*1024 + t*4 + q)) << shift;
        *selRB = (k - keff) + run;
      }
      run += b4[q];
    }
  }
}
__global__ void compact_k(const ull* __restrict__ ek, int N, const ull* __restrict__ selT,
                          ull* __restrict__ ckey, int* __restrict__ cidx, int* pM,
                          int* __restrict__ rank){
  int i = blockIdx.x*256+threadIdx.x; if(i>=N) return;
  ull key = ek[i];
  if(key >= *selT){
    int p = reserve_slot(pM);
    ckey[p]=key; cidx[p]=i;
    rank[i]=0;
  }
}
__global__ void rank_cand(const ull* __restrict__ ckey, const int* __restrict__ cidx, const int* pM,
                          int jlen, int* __restrict__ rank){
  __shared__ ull tk[1024];
  __shared__ int ti[1024];
  int M = *pM;
  if(blockIdx.x*256 >= M) return;
  int i = blockIdx.x*256+threadIdx.x;
  ull ki = 0; int ii = 0x7FFFFFFF;
  if(i<M){ ki=ckey[i]; ii=cidx[i]; }
  int jbeg = blockIdx.y*jlen;
  int jend = jbeg+jlen; if(jend>M) jend=M;
  int c0=0,c1=0,c2=0,c3=0;
  for(int bb=jbeg; bb<jend; bb+=1024){
    for(int j=threadIdx.x; j<1024; j+=256){
      int idx=bb+j;
      tk[j] = (idx<jend)? ckey[idx] : 0ULL;
      ti[j] = (idx<jend)? cidx[idx] : 0x7FFFFFFF;
    }
    __syncthreads();
    #pragma unroll 4
    for(int j=0;j<1024;j+=4){
      ull s0=tk[j],s1=tk[j+1],s2=tk[j+2],s3=tk[j+3];
      int a0=ti[j],a1=ti[j+1],a2=ti[j+2],a3=ti[j+3];
      c0 += (s0>ki)||(s0==ki && a0<ii);
      c1 += (s1>ki)||(s1==ki && a1<ii);
      c2 += (s2>ki)||(s2==ki && a2<ii);
      c3 += (s3>ki)||(s3==ki && a3<ii);
    }
    __syncthreads();
  }
  if(i<M){ int c=(c0+c1)+(c2+c3); if(c) atomicAdd(&rank[ii], c); }
}
__global__ void scatter_perm(const int* __restrict__ rank, int N, int k, int* __restrict__ perm){
  int i = blockIdx.x*256+threadIdx.x; if(i>=N) return;
  int r = rank[i]; if(r<k) perm[r]=i;
}
__global__ void pool_gather(const float* __restrict__ h, const double* __restrict__ score,
                            const int* __restrict__ perm, int k, float* __restrict__ outA){
  int idx = blockIdx.x*256+threadIdx.x; if(idx>=k*32) return;
  int r = idx>>5, g = (idx&31)*4;
  int p = perm[r]; float sc = (float)score[p];
  const float4 x = *(const float4*)(h + (size_t)p*128 + g);
  float4 o; o.x=x.x*sc; o.y=x.y*sc; o.z=x.z*sc; o.w=x.w*sc;
  *(float4*)(outA + (size_t)r*128 + g) = o;
}
__global__ void pos_gather(const float* __restrict__ posc, const int* __restrict__ perm, int k, float* __restrict__ posn){
  int idx = blockIdx.x*256+threadIdx.x; if(idx>=k*3) return;
  int r = idx/3, j = idx-r*3;
  posn[idx] = posc[perm[r]*3+j];
}

// ---------------- filter_adj ----------------
__global__ void filter_flags(const int* __restrict__ es, const int* __restrict__ ed, const int* pE, int Es,
                             const int* __restrict__ rank, int k, int* __restrict__ flags){
  int e = blockIdx.x*256+threadIdx.x; int E = getE(pE,Es); if(e>=E) return;
  flags[e] = (rank[es[e]]<k && rank[ed[e]]<k) ? 1 : 0;
}
__global__ void filter_write(const int* __restrict__ es, const int* __restrict__ ed, const int* pE, int Es,
                             const int* __restrict__ rank, int k, const int* __restrict__ scanout,
                             int* __restrict__ ns, int* __restrict__ nd){
  int e = blockIdx.x*256+threadIdx.x; int E = getE(pE,Es); if(e>=E) return;
  int rs = rank[es[e]], rd = rank[ed[e]];
  if(rs<k && rd<k){ int p = scanout[e]; ns[p]=rs; nd[p]=rd; }
}

// ---------------- output emit ----------------
__global__ void calc_offsets(const int* __restrict__ cnt, long long* __restrict__ offs){
  if(blockIdx.x==0 && threadIdx.x==0){
    long long E1 = cnt[C_E1], E2 = cnt[C_E2];
    long long o = (long long)KK2*128;
    offs[0]=0;
    offs[1]=o; o += 2*E2;
    offs[2]=o; o += 2*E1;
    offs[3]=o; o += 2*(long long)EE0;
    offs[4]=o; o += (long long)KK2*3;
    offs[5]=o; o += (long long)KK1*3;
    offs[6]=o; o += (long long)NN0*3;
    offs[7]=o; o += 3*E2;
    offs[8]=o; o += 3*E1;
    offs[9]=o;
  }
}
__global__ void emit_pe(const int* __restrict__ s, const int* __restrict__ d, const int* pE, int Es,
                        const long long* __restrict__ offs, int oi, float* __restrict__ out){
  int e = blockIdx.x*256+threadIdx.x; int E = getE(pE,Es); if(e>=E) return;
  long long o = offs[oi];
  out[o+e]   = (float)s[e];
  out[o+E+e] = (float)d[e];
}
__global__ void emit_pp(const float* __restrict__ p, int n, const long long* __restrict__ offs, int oi, float* __restrict__ out){
  int i = blockIdx.x*256+threadIdx.x; if(i>=n) return;
  out[offs[oi]+i] = p[i];
}
__global__ void emit_eas(const int* __restrict__ s, const int* __restrict__ d, const int* pE, int Es,
                         const float* __restrict__ pos, const long long* __restrict__ offs, int oi, float* __restrict__ out){
  int e = blockIdx.x*256+threadIdx.x; int E = getE(pE,Es); if(e>=E) return;
  long long o = offs[oi];
  int ss=s[e], dd=d[e];
  out[o+3*e+0] = pos[dd*3+0]-pos[ss*3+0];
  out[o+3*e+1] = pos[dd*3+1]-pos[ss*3+1];
  out[o+3*e+2] = pos[dd*3+2]-pos[ss*3+2];
}

// =======================================================================
extern "C" void kernel_launch(void* const* d_in, const int* in_sizes, int n_in,
                              void* d_out, int out_size, void* d_ws, size_t ws_size,
                              hipStream_t stream)
{
  const float* x    = (const float*)d_in[0];
  const float* yv   = (const float*)d_in[1];
  const float* pos0 = (const float*)d_in[2];
  const int*   ei   = (const int*)d_in[3];
  const float* Wl0  = (const float*)d_in[4];
  const float* Wr0  = (const float*)d_in[5];
  const float* We0  = (const float*)d_in[6];
  const float* a0   = (const float*)d_in[7];
  const float* b0   = (const float*)d_in[8];
  const float* Wls  = (const float*)d_in[9];
  const float* Wrs  = (const float*)d_in[10];
  const float* Wes  = (const float*)d_in[11];
  const float* atts = (const float*)d_in[12];
  const float* bs   = (const float*)d_in[13];
  const float* pWl  = (const float*)d_in[14];
  const float* pWr  = (const float*)d_in[15];
  const float* pWe  = (const float*)d_in[16];
  const float* pa   = (const float*)d_in[17];
  const float* pb   = (const float*)d_in[18];
  const float* linW = (const float*)d_in[19];
  const float* linb = (const float*)d_in[20];
  float* out = (float*)d_out;

  const int* eisrc = ei;
  const int* eidst = ei + EE0;

  char* base = (char*)d_ws; size_t off = 0;
  auto alloc = [&](size_t b)->void*{
    off = (off + 255) & ~(size_t)255;
    void* p = base + off; off += b; return p;
  };
  int*       cnt     = (int*)alloc(64*4);
  long long* offs    = (long long*)alloc(16*8);
  int*       bsums   = (int*)alloc(256*4);
  ull*       sel     = (ull*)alloc(2*8);
  int*       hist    = (int*)alloc((size_t)HBINS*4);
  int*       partial = (int*)alloc(2048*4);
  double*    xls     = (double*)alloc((size_t)NN0*8);
  double*    xrs     = (double*)alloc((size_t)NN0*8);
  double*    score   = (double*)alloc((size_t)NN0*8);
  ull*       ek      = (ull*)alloc((size_t)NN0*8);
  ull*       ckey    = (ull*)alloc((size_t)NN0*8);
  int*       cidx    = (int*)alloc((size_t)NN0*4);
  float*     loopatF = (float*)alloc((size_t)NN0*12);
  int*       rank    = (int*)alloc((size_t)NN0*4);
  int*       perm    = (int*)alloc((size_t)NN0*4);
  int*       cntsrc  = (int*)alloc((size_t)NN0*4);
  int*       starts  = (int*)alloc((size_t)(NN0+1)*4);
  int*       cursor  = (int*)alloc((size_t)NN0*4);
  int*       ccnt    = (int*)alloc((size_t)NN0*4);
  int*       dstarts = (int*)alloc((size_t)(NN0+1)*4);
  int*       cstarts = (int*)alloc((size_t)(NN0+1)*4);
  int*       eord    = (int*)alloc((size_t)EE0*4);
  int*       lens    = (int*)alloc((size_t)EE0*4);
  int*       l2scan  = (int*)alloc((size_t)(EE0+1)*4);
  int*       t2      = (int*)alloc((size_t)EE0*4);
  int*       flags   = (int*)alloc((size_t)EE0*4);
  int*       scanout = (int*)alloc((size_t)(EE0+1)*4);
  int*       eb0s    = (int*)alloc((size_t)EE0*4);
  int*       eb0d    = (int*)alloc((size_t)EE0*4);
  int*       eb1s    = (int*)alloc((size_t)EE0*4);
  int*       eb1d    = (int*)alloc((size_t)EE0*4);
  float*     pos1    = (float*)alloc((size_t)KK1*12);
  float*     pos2    = (float*)alloc((size_t)KK2*12);
  float*     A       = (float*)alloc((size_t)NN0*128*4);
  float*     B       = (float*)alloc((size_t)NN0*128*4);
  float*     h       = (float*)alloc((size_t)NN0*128*4);
  void*      uni     = alloc((size_t)(EE0+FLATMAX)*8);   // union: cpair (pool) / zbF (conv)
  if(off > ws_size) return;

  int*    cand  = (int*)B;       // dead during pool stage; see Round-5 alias note
  float*  zbF   = (float*)uni;
  ull*    cpair = (ull*)uni;
  ull*    selT  = sel;
  int*    selRB = (int*)(sel+1);

  hipMemsetAsync(cnt, 0, 64*4, stream);

  auto scan = [&](const int* in, int* sout, const int* pN, int Ns, int* total){
    int nb = CDIV(Ns+1, SCH);
    scan_p1<<<nb,256,0,stream>>>(in,pN,Ns,bsums);
    scan_p2<<<1,256,0,stream>>>(bsums,nb);
    scan_p3<<<nb,256,0,stream>>>(in,sout,pN,Ns,bsums,total);
  };

  auto build_csr_dst = [&](const int* es, const int* ed, const int* pE, int Emax, int N, const float* pcur){
    hipMemsetAsync(ccnt,0,(size_t)N*4,stream);
    count_src<<<CDIV(Emax,256),256,0,stream>>>(ed,pE,Emax,ccnt);
    scan(ccnt,dstarts,nullptr,N,nullptr);
    hipMemsetAsync(cursor,0,(size_t)N*4,stream);
    fill_eord<<<CDIV(Emax,256),256,0,stream>>>(ed,pE,Emax,dstarts,cursor,eord);
    loop_csr_f<<<CDIV(N,256),256,0,stream>>>(es,eord,dstarts,pcur,loopatF,N);
  };

  auto feat_conv = [&](const float* Wl, const float* Wr, const float* We, const float* att, const float* bias,
                       const int* es, const int* ed, const int* pE, int Emax, int N, const float* pcur,
                       bool conv0mode){
    if(conv0mode)
      gemm_k<0,true><<<CDIV(N,8),256,0,stream>>>(x,pcur,yv,Wl,Wr,nullptr,A,B,N);
    else
      gemm_k<1,true><<<CDIV(N,8),256,0,stream>>>(h,pcur,nullptr,Wl,Wr,nullptr,A,B,N);
    long long wt = (long long)(Emax+N)*64;
    feat_logits<<<(int)CDIV(wt,256),256,0,stream>>>(es,ed,pE,Emax,N,A,B,pcur,We,att,loopatF,zbF);
    feat_acc_csr<<<CDIV(N*64,256),256,0,stream>>>(es,eord,dstarts,pE,Emax,A,zbF,bias,h,N);
  };

  auto pool = [&](int l, int N, int k, const int* es, const int* ed, const int* pE, int Emax,
                  const float* pcur, float* pnext, int* ns, int* nd, int eslot, int cmslot){
    // src-CSR for 2-hop enumeration
    hipMemsetAsync(cntsrc, 0, (size_t)N*4, stream);
    count_src<<<CDIV(Emax,256),256,0,stream>>>(es,pE,Emax,cntsrc);
    scan(cntsrc,starts,nullptr,N,nullptr);
    hipMemsetAsync(cursor, 0, (size_t)N*4, stream);
    fill_t2<<<CDIV(Emax,256),256,0,stream>>>(es,ed,pE,Emax,starts,cursor,t2);
    edge_lens_k<<<CDIV(Emax,256),256,0,stream>>>(ed,pE,Emax,cntsrc,lens);
    scan(lens,l2scan,pE,Emax,cnt+C_T2);
    // candidate pairs (1-hop + 2-hop, dups kept), bucketed by dst
    hipMemsetAsync(ccnt, 0, (size_t)N*4, stream);
    cand1<<<CDIV(Emax,256),256,0,stream>>>(es,ed,pE,Emax,cpair,ccnt);
    cand2<<<CDIV(FLATMAX,256),256,0,stream>>>(es,ed,pE,Emax,l2scan,cnt+C_T2,starts,t2,cpair,ccnt);
    scan(ccnt,cstarts,nullptr,N,nullptr);
    hipMemsetAsync(cursor,0,(size_t)N*4,stream);
    cand_fill<<<CDIV(EE0+FLATMAX,256),256,0,stream>>>(cpair,pE,Emax,cnt+C_T2,cstarts,cursor,cand);
    // fused score GATv2 (fp64) with in-kernel dedup
    gemm_score<<<CDIV(N,256),256,0,stream>>>(h,pcur,pWl+l*131,pWr+l*131,xls,xrs,N);
    score_fused2<<<N,64,0,stream>>>(cand,cstarts,pcur,xls,xrs,pWe+l*3,pa+l,pb+l,score,N);
    // top-k: 2-round refine select (bits 63..43, then 42..22), then rank among candidates
    enc_scores<<<CDIV(N,256),256,0,stream>>>(score,N,ek,rank);
    hipMemsetAsync(sel,0,16,stream);
    for(int r=0;r<2;r++){
      int sh = 43 - 21*r;
      hipMemsetAsync(hist,0,(size_t)HBINS*4,stream);
      hist_g<<<CDIV(N,256),256,0,stream>>>(ek,N,sh,selT,hist);
      part21<<<2048,256,0,stream>>>(hist,partial);
      findbin_g<<<1,256,0,stream>>>(partial,hist,selT,selRB,k,sh);
    }
    compact_k<<<CDIV(N,256),256,0,stream>>>(ek,N,selT,ckey,cidx,cnt+cmslot,rank);
    {
      int jch = 32, jlen = CDIV(N,jch);
      dim3 g(CDIV(N,256), jch);
      rank_cand<<<g,256,0,stream>>>(ckey,cidx,cnt+cmslot,jlen,rank);
    }
    scatter_perm<<<CDIV(N,256),256,0,stream>>>(rank,N,k,perm);
    pool_gather<<<CDIV(k*32,256),256,0,stream>>>(h,score,perm,k,A);
    hipMemcpyAsync(h,A,(size_t)k*128*4,hipMemcpyDeviceToDevice,stream);
    pos_gather<<<CDIV(k*3,256),256,0,stream>>>(pcur,perm,k,pnext);
    filter_flags<<<CDIV(Emax,256),256,0,stream>>>(es,ed,pE,Emax,rank,k,flags);
    scan(flags,scanout,pE,Emax,cnt+eslot);
    filter_write<<<CDIV(Emax,256),256,0,stream>>>(es,ed,pE,Emax,rank,k,scanout,ns,nd);
  };

  // ================= pipeline =================
  build_csr_dst(eisrc,eidst,nullptr,EE0, NN0, pos0);
  feat_conv(Wl0,Wr0,We0,a0,b0, eisrc,eidst,nullptr,EE0, NN0, pos0, true);
  feat_conv(Wls+0*16768,Wrs+0*16768,Wes+0*384,atts+0*128,bs+0*128, eisrc,eidst,nullptr,EE0, NN0, pos0, false);
  pool(0, NN0, KK1, eisrc,eidst,nullptr,EE0, pos0,pos1, eb0s,eb0d, C_E1, C_M0);
  build_csr_dst(eb0s,eb0d,cnt+C_E1,EE0, KK1, pos1);
  feat_conv(Wls+1*16768,Wrs+1*16768,Wes+1*384,atts+1*128,bs+1*128, eb0s,eb0d,cnt+C_E1,EE0, KK1, pos1, false);
  pool(1, KK1, KK2, eb0s,eb0d,cnt+C_E1,EE0, pos1,pos2, eb1s,eb1d, C_E2, C_M1);
  build_csr_dst(eb1s,eb1d,cnt+C_E2,EE0, KK2, pos2);
  feat_conv(Wls+2*16768,Wrs+2*16768,Wes+2*384,atts+2*128,bs+2*128, eb1s,eb1d,cnt+C_E2,EE0, KK2, pos2, false);
  feat_conv(Wls+3*16768,Wrs+3*16768,Wes+3*384,atts+3*128,bs+3*128, eb1s,eb1d,cnt+C_E2,EE0, KK2, pos2, false);
  gemm_k<2,false><<<CDIV(KK2,8),256,0,stream>>>(h,nullptr,nullptr,linW,nullptr,linb,out,nullptr,KK2);

  calc_offsets<<<1,32,0,stream>>>(cnt,offs);
  emit_pe <<<CDIV(EE0,256),256,0,stream>>>(eb1s,eb1d,cnt+C_E2,EE0,offs,1,out);
  emit_pe <<<CDIV(EE0,256),256,0,stream>>>(eb0s,eb0d,cnt+C_E1,EE0,offs,2,out);
  emit_pe <<<CDIV(EE0,256),256,0,stream>>>(eisrc,eidst,nullptr,EE0,offs,3,out);
  emit_pp <<<CDIV(KK2*3,256),256,0,stream>>>(pos2,KK2*3,offs,4,out);
  emit_pp <<<CDIV(KK1*3,256),256,0,stream>>>(pos1,KK1*3,offs,5,out);
  emit_pp <<<CDIV(NN0*3,256),256,0,stream>>>(pos0,NN0*3,offs,6,out);
  emit_eas<<<CDIV(EE0,256),256,0,stream>>>(eb1s,eb1d,cnt+C_E2,EE0,pos2,offs,7,out);
  emit_eas<<<CDIV(EE0,256),256,0,stream>>>(eb0s,eb0d,cnt+C_E1,EE0,pos1,offs,8,out);
  emit_eas<<<CDIV(EE0,256),256,0,stream>>>(eisrc,eidst,nullptr,EE0,pos0,offs,9,out);
}